// Round 13
// baseline (738.413 us; speedup 1.0000x reference)
//
#include <hip/hip_runtime.h>
#include <math.h>

#define NN 25000
#define EE 400000
#define LL 3
#define LNEPS 1e-5f
#define EB 64

typedef __attribute__((ext_vector_type(8))) short short8;
typedef __attribute__((ext_vector_type(16))) float f32x16;

__device__ __forceinline__ float lrelu(float x, float s) { return fmaxf(x, x * s); }

__device__ __forceinline__ unsigned int pack_bf2(float lo, float hi) {
    unsigned int ul = __float_as_uint(lo), uh = __float_as_uint(hi);
    ul = (ul + 0x7FFFu + ((ul >> 16) & 1u)) >> 16;
    uh = (uh + 0x7FFFu + ((uh >> 16) & 1u)) >> 16;
    return (uh << 16) | (ul & 0xFFFFu);
}
__device__ __forceinline__ float bf_lo(unsigned int u) { return __uint_as_float(u << 16); }
__device__ __forceinline__ float bf_hi(unsigned int u) { return __uint_as_float(u & 0xFFFF0000u); }

// 128-thread block LN stats (2 waves)
__device__ __forceinline__ void ln_stats128(float v, float* red, float& mean, float& inv) {
    float sm = v, sq = v * v;
#pragma unroll
    for (int m = 32; m >= 1; m >>= 1) { sm += __shfl_xor(sm, m); sq += __shfl_xor(sq, m); }
    __syncthreads();
    if ((threadIdx.x & 63) == 0) { red[(threadIdx.x >> 6) * 2] = sm; red[(threadIdx.x >> 6) * 2 + 1] = sq; }
    __syncthreads();
    sm = red[0] + red[2]; sq = red[1] + red[3];
    mean = sm * (1.f / 128.f);
    float var = sq * (1.f / 128.f) - mean * mean;
    inv = rsqrtf(var + LNEPS);
}

// ================= edge sorting (counting sort by dst) =================
__global__ void k_hist(const int* __restrict__ dst, int* __restrict__ cnt, int ne)
{
    int i = blockIdx.x * 256 + threadIdx.x;
    if (i < ne) atomicAdd(&cnt[dst[i]], 1);
}

__global__ __launch_bounds__(1024) void k_scan(const int* __restrict__ cnt,
                                               int* __restrict__ starts, int n)
{
    __shared__ int tot[1024];
    int t = threadIdx.x;
    const int PER = (n + 1023) >> 10;
    int i0 = t * PER;
    int s = 0;
    for (int k = 0; k < PER; ++k) { int i = i0 + k; s += (i < n) ? cnt[i] : 0; }
    tot[t] = s;
    __syncthreads();
    for (int off = 1; off < 1024; off <<= 1) {
        int x = (t >= off) ? tot[t - off] : 0;
        __syncthreads();
        tot[t] += x;
        __syncthreads();
    }
    int run = (t > 0) ? tot[t - 1] : 0;
    for (int k = 0; k < PER; ++k) {
        int i = i0 + k;
        if (i < n) { starts[i] = run; run += cnt[i]; }
    }
    if (t == 1023) starts[n] = tot[1023];
}

__global__ void k_scatter(const int* __restrict__ src, const int* __restrict__ dst,
                          const float* __restrict__ ea, int* __restrict__ cursor,
                          int* __restrict__ s_src, int* __restrict__ s_dst,
                          float* __restrict__ s_ea, int ne)
{
    int i = blockIdx.x * 256 + threadIdx.x;
    if (i >= ne) return;
    int d = dst[i];
    int pos = atomicAdd(&cursor[d], 1);
    s_src[pos] = src[i];
    s_dst[pos] = d;
    s_ea[pos] = ea[i];
}

// ================= weight pre-pack: fp32 [128x128] -> bf16 B-fragment order ====
// mat m: 0..2 gat_w[i]; 3..8 ec_w1 layer (m-3)>>1 half (m-3)&1; 9..11 ec_w2[i]; 12 emb_w
__global__ void k_prep(const float* __restrict__ gat_w, const float* __restrict__ ec_w1,
                       const float* __restrict__ ec_w2, const float* __restrict__ emb_w,
                       uint4* __restrict__ wf)
{
    int g = blockIdx.x * 256 + threadIdx.x;   // < 13*2048
    int m = g >> 11, f = g & 2047;
    const float* srcm;
    if (m < 3) srcm = gat_w + (size_t)m * 16384;
    else if (m < 9) { int t2 = m - 3; srcm = ec_w1 + (size_t)(t2 >> 1) * 32768 + (size_t)(t2 & 1) * 16384; }
    else if (m < 12) srcm = ec_w2 + (size_t)(m - 9) * 16384;
    else srcm = emb_w;
    int l = f & 63, ks = (f >> 6) & 7, nb = f >> 9;
    int k0 = ks * 16 + (l >> 5) * 8, col = nb * 32 + (l & 31);
    const float* wp = srcm + (size_t)k0 * 128 + col;
    uint4 r;
    r.x = pack_bf2(wp[0],   wp[128]);
    r.y = pack_bf2(wp[256], wp[384]);
    r.z = pack_bf2(wp[512], wp[640]);
    r.w = pack_bf2(wp[768], wp[896]);
    wf[g] = r;
}

// ---- MFMA embedding: h = x0 = lrelu(LN(x @ emb_w + emb_b)) ----
__global__ __launch_bounds__(256) void k_emb(
    const float* __restrict__ in, const uint4* __restrict__ wfm,
    const float* __restrict__ bias, const float* __restrict__ g,
    const float* __restrict__ be, float* __restrict__ h,
    float* __restrict__ x0, int nrows)
{
    __shared__ __align__(16) unsigned int sA[64 * 64];
    __shared__ __align__(16) unsigned int sW[2048 * 4];   // 32KB, reused as sU
    float* sU = (float*)sW;
    const int tid = threadIdx.x;
    const int r0 = blockIdx.x * 64;
    {
        int row = tid >> 2, q = tid & 3;
        const float* srcp = in + (size_t)(r0 + row) * 128 + q * 32;
        bool ok = (r0 + row) < nrows;
#pragma unroll
        for (int i = 0; i < 8; ++i) {
            float4 v = ok ? *(const float4*)&srcp[i * 4] : make_float4(0.f, 0.f, 0.f, 0.f);
            int cu = (q * 16 + i * 2) ^ ((row & 15) << 2);
            *(uint2*)&sA[row * 64 + cu] = make_uint2(pack_bf2(v.x, v.y), pack_bf2(v.z, v.w));
        }
    }
    {
        uint4* sW4 = (uint4*)sW;
#pragma unroll
        for (int i = 0; i < 8; ++i) sW4[tid + 256 * i] = wfm[tid + 256 * i];
    }
    __syncthreads();
    const int w = tid >> 6, l = tid & 63;
    const int m0 = (w >> 1) * 32, nhalf = (w & 1);
    f32x16 acc0 = {}, acc1 = {};
#pragma unroll
    for (int ks = 0; ks < 8; ++ks) {
        int rw = m0 + (l & 31);
        int cu = (ks * 8 + (l >> 5) * 4) ^ ((rw & 15) << 2);
        short8 a = *(const short8*)&sA[rw * 64 + cu];
        short8 b0 = *(const short8*)&sW[((nhalf * 16 + ks) * 64 + l) * 4];
        short8 b1 = *(const short8*)&sW[(((nhalf * 2 + 1) * 8 + ks) * 64 + l) * 4];
        acc0 = __builtin_amdgcn_mfma_f32_32x32x16_bf16(a, b0, acc0, 0, 0, 0);
        acc1 = __builtin_amdgcn_mfma_f32_32x32x16_bf16(a, b1, acc1, 0, 0, 0);
    }
    __syncthreads();   // all waves done reading sW
    {
        int colbase = nhalf * 64 + (l & 31);
        float bb0 = bias[colbase], bb1 = bias[colbase + 32];
#pragma unroll
        for (int r = 0; r < 16; ++r) {
            int rw = m0 + (r & 3) + 8 * (r >> 2) + 4 * (l >> 5);
            sU[rw * 128 + colbase]      = acc0[r] + bb0;
            sU[rw * 128 + colbase + 32] = acc1[r] + bb1;
        }
    }
    __syncthreads();
    // LN epilogue: 4 waves x 16 rows
    float2 gv = *(const float2*)&g[l * 2];
    float2 bv = *(const float2*)&be[l * 2];
    for (int it = 0; it < 16; ++it) {
        int rw = w * 16 + it;
        int grow = r0 + rw;
        if (grow >= nrows) break;
        float2 v = *(const float2*)&sU[rw * 128 + l * 2];
        float sm = v.x + v.y, sq = v.x * v.x + v.y * v.y;
#pragma unroll
        for (int m = 32; m >= 1; m >>= 1) { sm += __shfl_xor(sm, m); sq += __shfl_xor(sq, m); }
        float mean = sm * (1.f / 128.f);
        float var = sq * (1.f / 128.f) - mean * mean;
        float inv = rsqrtf(var + LNEPS);
        float o0 = lrelu((v.x - mean) * inv * gv.x + bv.x, 0.01f);
        float o1 = lrelu((v.y - mean) * inv * gv.y + bv.y, 0.01f);
        unsigned off = (unsigned)grow * 128u + (unsigned)(l * 2);
        *(float2*)&h[off]  = make_float2(o0, o1);
        *(float2*)&x0[off] = make_float2(o0, o1);
    }
}

// ---- MFMA 3-in-1 node GEMM: {ht, A'(+b1), B} = act @ {Wht, WA, WB}, packed bf16 out.
//      mode 0: act = in (fp32 h rows).
//      mode 1: act = lrelu(LN(xsum + gbias + selfloop))            (fused k_norm8, no residual)
//      mode 2: ... + x0 residual, x0 updated                        (fused k_norm8, residual)
__global__ __launch_bounds__(256) void k_gemm3(
    const float* __restrict__ in, const unsigned* __restrict__ htp_in,
    const float* __restrict__ selfe, const float* __restrict__ denom,
    const float* __restrict__ gbias, const float* __restrict__ ng,
    const float* __restrict__ nb, float* __restrict__ x0,
    const uint4* __restrict__ wf,
    int mht, int mA, int mB, const float* __restrict__ bA,
    unsigned* __restrict__ o0, unsigned* __restrict__ o1, unsigned* __restrict__ o2,
    int nrows, int mode)
{
    __shared__ __align__(16) unsigned int sA[64 * 64];     // 16KB bf16 tile, XOR-swizzled
    __shared__ __align__(16) unsigned int sW[2048 * 4];    // 32KB B-fragments
    const int tid = threadIdx.x;
    const int r0 = blockIdx.x * 64;
    {
        int row = tid >> 2, q = tid & 3;
        int node = r0 + row;
        bool ok = node < nrows;
        if (mode == 0) {
            const float* srcp = in + (size_t)node * 128 + q * 32;
#pragma unroll
            for (int i = 0; i < 8; ++i) {
                float4 v = ok ? *(const float4*)&srcp[i * 4] : make_float4(0.f, 0.f, 0.f, 0.f);
                int cu = (q * 16 + i * 2) ^ ((row & 15) << 2);
                *(uint2*)&sA[row * 64 + cu] = make_uint2(pack_bf2(v.x, v.y), pack_bf2(v.z, v.w));
            }
        } else {
            // fused norm of previous layer: LN(xsum + gbias + ht_prev*alpha) (+x0)
            unsigned off128 = (unsigned)node * 128u + (unsigned)(q * 32);
            unsigned off64  = (unsigned)node * 64u + (unsigned)(q * 16);
            int hd = q >> 1;
            float alpha = ok ? (selfe[node * 2 + hd] / denom[node * 2 + hd]) : 0.f;
            float4 vv[8];
            float sm = 0.f, sq = 0.f;
#pragma unroll
            for (int i = 0; i < 8; ++i) {
                float4 v = ok ? *(const float4*)&in[off128 + i * 4] : make_float4(0.f, 0.f, 0.f, 0.f);
                uint2 hvp = ok ? *(const uint2*)&htp_in[off64 + i * 2] : make_uint2(0u, 0u);
                float4 gbv = *(const float4*)&gbias[q * 32 + i * 4];
                v.x += gbv.x + bf_lo(hvp.x) * alpha;
                v.y += gbv.y + bf_hi(hvp.x) * alpha;
                v.z += gbv.z + bf_lo(hvp.y) * alpha;
                v.w += gbv.w + bf_hi(hvp.y) * alpha;
                vv[i] = v;
                sm += v.x + v.y + v.z + v.w;
                sq += v.x * v.x + v.y * v.y + v.z * v.z + v.w * v.w;
            }
            sm += __shfl_xor(sm, 1); sq += __shfl_xor(sq, 1);
            sm += __shfl_xor(sm, 2); sq += __shfl_xor(sq, 2);
            float mean = sm * (1.f / 128.f);
            float inv = rsqrtf(sq * (1.f / 128.f) - mean * mean + LNEPS);
#pragma unroll
            for (int i = 0; i < 8; ++i) {
                float4 v = vv[i];
                float4 gv = *(const float4*)&ng[q * 32 + i * 4];
                float4 bv = *(const float4*)&nb[q * 32 + i * 4];
                float w0 = lrelu((v.x - mean) * inv * gv.x + bv.x, 0.01f);
                float w1 = lrelu((v.y - mean) * inv * gv.y + bv.y, 0.01f);
                float w2 = lrelu((v.z - mean) * inv * gv.z + bv.z, 0.01f);
                float w3 = lrelu((v.w - mean) * inv * gv.w + bv.w, 0.01f);
                if (mode == 2 && ok) {
                    float4 xv = *(const float4*)&x0[off128 + i * 4];
                    w0 += xv.x; w1 += xv.y; w2 += xv.z; w3 += xv.w;
                    *(float4*)&x0[off128 + i * 4] = make_float4(w0, w1, w2, w3);
                }
                int cu = (q * 16 + i * 2) ^ ((row & 15) << 2);
                *(uint2*)&sA[row * 64 + cu] = make_uint2(pack_bf2(w0, w1), pack_bf2(w2, w3));
            }
        }
    }
    __syncthreads();
    const int w = tid >> 6, l = tid & 63;
    const int m0 = (w >> 1) * 32, nhalf = (w & 1);
    short8 af[8];
#pragma unroll
    for (int ks = 0; ks < 8; ++ks) {
        int row = m0 + (l & 31);
        int cu = (ks * 8 + (l >> 5) * 4) ^ ((row & 15) << 2);
        af[ks] = *(const short8*)&sA[row * 64 + cu];
    }
    const int c = l & 31;
    const bool evenl = (c & 1) == 0;
    const unsigned uidx = (unsigned)(nhalf * 32 + (evenl ? (c >> 1) : (16 + (c >> 1))));
    auto do_mat = [&](int mat, unsigned* out, const float* bp) {
        __syncthreads();
        {
            const uint4* wsrc = wf + (size_t)mat * 2048;
            uint4* sW4 = (uint4*)sW;
#pragma unroll
            for (int i = 0; i < 8; ++i) sW4[tid + 256 * i] = wsrc[tid + 256 * i];
        }
        __syncthreads();
        f32x16 acc0 = {}, acc1 = {};
        const int nb0 = nhalf * 2;
#pragma unroll
        for (int ks = 0; ks < 8; ++ks) {
            short8 b0 = *(const short8*)&sW[((nb0 * 8 + ks) * 64 + l) * 4];
            short8 b1v = *(const short8*)&sW[(((nb0 + 1) * 8 + ks) * 64 + l) * 4];
            acc0 = __builtin_amdgcn_mfma_f32_32x32x16_bf16(af[ks], b0, acc0, 0, 0, 0);
            acc1 = __builtin_amdgcn_mfma_f32_32x32x16_bf16(af[ks], b1v, acc1, 0, 0, 0);
        }
        int colbase = nhalf * 64 + c;
        float badd0 = bp ? bp[colbase] : 0.f;
        float badd1 = bp ? bp[colbase + 32] : 0.f;
#pragma unroll
        for (int r = 0; r < 16; ++r) {
            float v0 = acc0[r] + badd0;
            float v1 = acc1[r] + badd1;
            float v0p = __shfl_xor(v0, 1);
            float v1p = __shfl_xor(v1, 1);
            int row = r0 + m0 + (r & 3) + 8 * (r >> 2) + 4 * (l >> 5);
            if (row < nrows) {
                unsigned val = evenl ? pack_bf2(v0, v0p) : pack_bf2(v1p, v1);
                out[(unsigned)row * 64u + uidx] = val;
            }
        }
    };
    do_mat(mht, o0, nullptr);
    do_mat(mA, o1, bA);
    do_mat(mB, o2, nullptr);
}

// ---- merged per-node pass: GAT scores + selfe/denom init + row sums of A',B ----
__global__ __launch_bounds__(512) void k_node_scores(
    const unsigned* __restrict__ htp, const unsigned* __restrict__ Apk,
    const unsigned* __restrict__ Bpk,
    const float* __restrict__ as_, const float* __restrict__ ad_,
    float* __restrict__ a_s, float* __restrict__ a_d,
    float* __restrict__ denom, float* __restrict__ selfe,
    float* __restrict__ rsA, float* __restrict__ rsB, int n)
{
    int wv = threadIdx.x >> 6, ln = threadIdx.x & 63;
    int node = blockIdx.x * 8 + wv;
    if (node >= n) return;
    unsigned off = (unsigned)node * 64u + (unsigned)ln;
    unsigned hv = htp[off], av = Apk[off], bv = Bpk[off];
    float h0 = bf_lo(hv), h1 = bf_hi(hv);
    float2 wsv = *(const float2*)&as_[ln * 2];
    float2 wdv = *(const float2*)&ad_[ln * 2];
    float ss = h0 * wsv.x + h1 * wsv.y;
    float sd = h0 * wdv.x + h1 * wdv.y;
    float sa = bf_lo(av) + bf_hi(av), sb = bf_lo(bv) + bf_hi(bv);
#pragma unroll
    for (int m = 16; m >= 1; m >>= 1) {
        ss += __shfl_xor(ss, m); sd += __shfl_xor(sd, m);
        sa += __shfl_xor(sa, m); sb += __shfl_xor(sb, m);
    }
    float sa2 = sa + __shfl_xor(sa, 32);
    float sb2 = sb + __shfl_xor(sb, 32);
    if ((ln & 31) == 0) {
        int hd = ln >> 5;
        a_s[node * 2 + hd] = ss;
        a_d[node * 2 + hd] = sd;
        float ev = expf(lrelu(ss + sd, 0.2f));
        denom[node * 2 + hd] = ev;
        selfe[node * 2 + hd] = ev;
        if (hd == 0) { rsA[node] = sa2; rsB[node] = sb2; }
    }
}

// ---- accumulate exp(e) per dst over sorted edges (run-merged), store expo, zero xsum ----
__global__ void k_edge_denom2(const int* __restrict__ s_src, const int* __restrict__ s_dst,
                              const float* __restrict__ a_s, const float* __restrict__ a_d,
                              float* __restrict__ denom, float* __restrict__ expo,
                              float4* __restrict__ xz, int nz4, int ne)
{
    int gtid = blockIdx.x * 256 + threadIdx.x;
    for (int i = gtid; i < nz4; i += gridDim.x * 256)
        xz[i] = make_float4(0.f, 0.f, 0.f, 0.f);
    int base = gtid * 8;
    if (base >= ne) return;
    int curd = -1;
    float acc0 = 0.f, acc1 = 0.f;
    for (int k = 0; k < 8; ++k) {
        int e = base + k;
        if (e >= ne) break;
        int s = s_src[e], d = s_dst[e];
        float v0 = expf(lrelu(a_s[(unsigned)(s * 2)]     + a_d[(unsigned)(d * 2)],     0.2f));
        float v1 = expf(lrelu(a_s[(unsigned)(s * 2 + 1)] + a_d[(unsigned)(d * 2 + 1)], 0.2f));
        *(float2*)&expo[(unsigned)e * 2] = make_float2(v0, v1);
        if (d != curd) {
            if (curd >= 0) { atomicAdd(&denom[curd * 2], acc0); atomicAdd(&denom[curd * 2 + 1], acc1); }
            curd = d; acc0 = v0; acc1 = v1;
        } else { acc0 += v0; acc1 += v1; }
    }
    if (curd >= 0) { atomicAdd(&denom[curd * 2], acc0); atomicAdd(&denom[curd * 2 + 1], acc1); }
}

// ---- fused edge kernel (dst-sorted): EdgeConv MLP (MFMA) + GAT, run-merged scatter.
//      LDS diet: u stored as packed bf16 overlaying sT32 (sWB stays W2-only) ->
//      ~37KB/block -> 4 blocks/CU occupancy cap.
__global__ __launch_bounds__(512) void k_edge_main(
    const unsigned* __restrict__ Apk, const unsigned* __restrict__ Bpk,
    const unsigned* __restrict__ htp,
    const int* __restrict__ s_src, const int* __restrict__ s_dst,
    const float* __restrict__ s_ea,
    const float* __restrict__ expo, const float* __restrict__ denom,
    const uint4* __restrict__ w2f,
    const float* __restrict__ rsA, const float* __restrict__ rsB,
    const float* __restrict__ g1, const float* __restrict__ be1,
    const float* __restrict__ b2, const float* __restrict__ g2, const float* __restrict__ be2,
    float* __restrict__ xsum, int ne)
{
    __shared__ __align__(16) unsigned int sWB[2048 * 4];   // W2 bf16 B-fragments (32KB), whole kernel
    __shared__ __align__(16) unsigned int sT32[EB * 64];   // t tile bf16 pairs; reused as packed u
    __shared__ int   sS[EB], sD[EB];
    __shared__ float sEA[EB], sM[EB];
    __shared__ float sAl[EB * 2];
    __shared__ float sMean[EB], sInv[EB];
    __shared__ float sG1[128], sE1[128], sB2[128], sG2[128], sE2[128];
    unsigned* sUp = sT32;   // packed bf16 u-tile [64][64] uints, after phase-2 barrier

    const int tid = threadIdx.x;
    {   // stage W2 fragments: pure copy (pre-packed by k_prep)
        uint4* sWB4 = (uint4*)sWB;
#pragma unroll
        for (int i = 0; i < 4; ++i) { int f = tid + 512 * i; sWB4[f] = w2f[f]; }
    }
    if (tid < 128) {
        sG1[tid] = g1[tid]; sE1[tid] = be1[tid];
        sB2[tid] = b2[tid]; sG2[tid] = g2[tid]; sE2[tid] = be2[tid];
    }
    const int e0 = blockIdx.x * EB;
    const int nev = (ne - e0 < EB) ? (ne - e0) : EB;
    if (tid < EB) {
        if (tid < nev) {
            int s = s_src[e0 + tid], d = s_dst[e0 + tid];
            sS[tid] = s; sD[tid] = d; sEA[tid] = s_ea[e0 + tid];
            sM[tid] = (rsA[s] + rsB[d]) * (1.f / 128.f);
        } else { sS[tid] = 0; sD[tid] = -1; sEA[tid] = 0.f; sM[tid] = 0.f; }
    }
    if (tid < 2 * EB) {
        int le = tid >> 1, hd = tid & 1;
        float al = 0.f;
        if (le < nev) {
            int e = e0 + le;
            int d = s_dst[e];
            al = expo[(unsigned)e * 2 + hd] / denom[(unsigned)(d * 2 + hd)];
        }
        sAl[le * 2 + hd] = al;
    }
    __syncthreads();

    const int wv = tid >> 6, ln = tid & 63;
    const int half = ln >> 5, lc = ln & 31;

    // phase 1 (pair-mode): lanes 0-31 -> edge 2j, lanes 32-63 -> edge 2j+1.
    {
        const float g10 = sG1[lc * 4], g11 = sG1[lc * 4 + 1], g12 = sG1[lc * 4 + 2], g13 = sG1[lc * 4 + 3];
        const float e10 = sE1[lc * 4], e11 = sE1[lc * 4 + 1], e12 = sE1[lc * 4 + 2], e13 = sE1[lc * 4 + 3];
        for (int j = 0; j < 4; ++j) {
            int e = wv * 8 + j * 2 + half;
            if (e < nev) {
                unsigned s = (unsigned)sS[e], d = (unsigned)sD[e];
                float mean = sM[e];
                uint2 av = *(const uint2*)&Apk[s * 64u + (unsigned)(lc * 2)];
                uint2 bv = *(const uint2*)&Bpk[d * 64u + (unsigned)(lc * 2)];
                float v0 = bf_lo(av.x) + bf_lo(bv.x) - mean;
                float v1 = bf_hi(av.x) + bf_hi(bv.x) - mean;
                float v2 = bf_lo(av.y) + bf_lo(bv.y) - mean;
                float v3 = bf_hi(av.y) + bf_hi(bv.y) - mean;
                float sq = v0 * v0 + v1 * v1 + v2 * v2 + v3 * v3;
#pragma unroll
                for (int m = 16; m >= 1; m >>= 1) sq += __shfl_xor(sq, m);
                float inv = rsqrtf(sq * (1.f / 128.f) + LNEPS);
                float t0 = lrelu(v0 * inv * g10 + e10, 0.2f);
                float t1 = lrelu(v1 * inv * g11 + e11, 0.2f);
                float t2 = lrelu(v2 * inv * g12 + e12, 0.2f);
                float t3 = lrelu(v3 * inv * g13 + e13, 0.2f);
                int cu = (lc * 2) ^ ((e & 15) << 2);
                *(uint2*)&sT32[e * 64 + cu] = make_uint2(pack_bf2(t0, t1), pack_bf2(t2, t3));
            }
        }
    }
    __syncthreads();

    // phase 2: u = t @ W2 via MFMA. 8 waves, each one 32x32 output tile.
    // After the barrier, sT32 is reused as the packed bf16 u-tile (sUp).
    {
        const int w = wv, l = ln;
        const int m0 = (w >> 2) * 32, n0 = (w & 3) * 32;
        f32x16 acc = {};
#pragma unroll
        for (int ks = 0; ks < 8; ++ks) {
            int row = m0 + (l & 31);
            int colu = (ks * 8 + (l >> 5) * 4) ^ ((row & 15) << 2);
            short8 a = *(const short8*)&sT32[row * 64 + colu];
            short8 b = *(const short8*)&sWB[((((w & 3) * 8 + ks) * 64 + l)) * 4];
            acc = __builtin_amdgcn_mfma_f32_32x32x16_bf16(a, b, acc, 0, 0, 0);
        }
        __syncthreads();   // all waves done reading sT32 before overwriting as sUp
        const int c = l & 31;
        float b2c = sB2[n0 + c];
        const bool evenc = (c & 1) == 0;
        const unsigned ubase = (unsigned)((w & 3) * 16 + (c >> 1));
#pragma unroll
        for (int r = 0; r < 16; ++r) {
            float v = acc[r] + b2c;
            float vp = __shfl_xor(v, 1);
            if (evenc) {
                int row = m0 + (r & 3) + 8 * (r >> 2) + 4 * (l >> 5);
                sUp[(unsigned)row * 64u + ubase] = pack_bf2(v, vp);
            }
        }
    }
    __syncthreads();

    // phase 2.5 (pair-mode stats): each wave computes mean/inv for its own 8 edges.
    for (int j = 0; j < 4; ++j) {
        int e = wv * 8 + j * 2 + half;
        if (e < nev) {
            uint2 up = *(const uint2*)&sUp[(unsigned)e * 64u + (unsigned)(lc * 2)];
            float u0 = bf_lo(up.x), u1 = bf_hi(up.x), u2 = bf_lo(up.y), u3 = bf_hi(up.y);
            float sm = u0 + u1 + u2 + u3;
            float sq = u0 * u0 + u1 * u1 + u2 * u2 + u3 * u3;
#pragma unroll
            for (int m = 16; m >= 1; m >>= 1) { sm += __shfl_xor(sm, m); sq += __shfl_xor(sq, m); }
            if (lc == 0) {
                float mean = sm * (1.f / 128.f);
                sMean[e] = mean;
                sInv[e] = rsqrtf(sq * (1.f / 128.f) - mean * mean + LNEPS);
            }
        }
    }

    // phase 3: LN(u)+lrelu (stats from LDS), *edge_attr, + GAT ht[src]*alpha;
    // run-merged atomic scatter (64-lane per edge, 8-edge merge window)
    {
        const unsigned ln2 = (unsigned)(ln * 2);
        const float g2a = sG2[ln * 2], g2b = sG2[ln * 2 + 1];
        const float e2a = sE2[ln * 2], e2b = sE2[ln * 2 + 1];
        int curd = -1;
        float acc0 = 0.f, acc1 = 0.f;
        for (int j = 0; j < 8; ++j) {
            int e = wv * 8 + j;
            if (e >= nev) break;
            unsigned s = (unsigned)sS[e];
            int d = sD[e];
            float mean = sMean[e], inv = sInv[e];
            unsigned up = sUp[(unsigned)e * 64u + (unsigned)ln];
            float eav = sEA[e];
            float v0 = lrelu((bf_lo(up) - mean) * inv * g2a + e2a, 0.2f) * eav;
            float v1 = lrelu((bf_hi(up) - mean) * inv * g2b + e2b, 0.2f) * eav;
            float al = sAl[e * 2 + half];
            unsigned hv = htp[s * 64u + ln];
            v0 += bf_lo(hv) * al;
            v1 += bf_hi(hv) * al;
            if (d != curd) {
                if (curd >= 0) {
                    atomicAdd(&xsum[(unsigned)curd * 128u + ln2], acc0);
                    atomicAdd(&xsum[(unsigned)curd * 128u + ln2 + 1], acc1);
                }
                curd = d; acc0 = v0; acc1 = v1;
            } else { acc0 += v0; acc1 += v1; }
        }
        if (curd >= 0) {
            atomicAdd(&xsum[(unsigned)curd * 128u + ln2], acc0);
            atomicAdd(&xsum[(unsigned)curd * 128u + ln2 + 1], acc1);
        }
    }
}

// ---- h = lrelu(LN(xsum + gat_bias + selfloop)) (+ x0 residual), wave-per-node ----
__global__ __launch_bounds__(512) void k_norm8(const float* __restrict__ xsum,
                                               const unsigned* __restrict__ htp,
                                               const float* __restrict__ selfe,
                                               const float* __restrict__ denom,
                                               const float* __restrict__ gbias,
                                               const float* __restrict__ g,
                                               const float* __restrict__ b,
                                               float* __restrict__ x0,
                                               float* __restrict__ h, int n, int layer)
{
    int wv = threadIdx.x >> 6, ln = threadIdx.x & 63;
    int node = blockIdx.x * 8 + wv;
    if (node >= n) return;
    unsigned off = (unsigned)node * 128u + (unsigned)(ln * 2);
    int hd = ln >> 5;
    float alpha = selfe[node * 2 + hd] / denom[node * 2 + hd];
    unsigned hv = htp[(unsigned)node * 64u + (unsigned)ln];
    float2 gb = *(const float2*)&gbias[ln * 2];
    float2 v = *(const float2*)&xsum[off];
    v.x += gb.x + bf_lo(hv) * alpha;
    v.y += gb.y + bf_hi(hv) * alpha;
    float sm = v.x + v.y, sq = v.x * v.x + v.y * v.y;
#pragma unroll
    for (int m = 32; m >= 1; m >>= 1) { sm += __shfl_xor(sm, m); sq += __shfl_xor(sq, m); }
    float mean = sm * (1.f / 128.f);
    float var = sq * (1.f / 128.f) - mean * mean;
    float inv = rsqrtf(var + LNEPS);
    float2 gv = *(const float2*)&g[ln * 2];
    float2 bv = *(const float2*)&b[ln * 2];
    float val0 = lrelu((v.x - mean) * inv * gv.x + bv.x, 0.01f);
    float val1 = lrelu((v.y - mean) * inv * gv.y + bv.y, 0.01f);
    if (layer > 0) {
        float2 x0v = *(const float2*)&x0[off];
        val0 += x0v.x; val1 += x0v.y;
        *(float2*)&x0[off] = make_float2(val0, val1);
    }
    *(float2*)&h[off] = make_float2(val0, val1);
}

// ---- pooling attention scores (one node per wave) ----
__global__ __launch_bounds__(256) void k_pool_score(const float* __restrict__ h,
    const float* __restrict__ w1, const float* __restrict__ b1,
    const float* __restrict__ w2, const float* __restrict__ b2,
    float* __restrict__ score, int n)
{
    int wv = threadIdx.x >> 6, ln = threadIdx.x & 63;
    int node = blockIdx.x * 4 + wv;
    if (node >= n) return;
    float acc = b1[ln];
    const float* hr = h + (size_t)node * 128;
    for (int k = 0; k < 128; ++k) acc += hr[k] * w1[k * 64 + ln];
    acc = lrelu(acc, 0.01f) * w2[ln];
#pragma unroll
    for (int m = 32; m >= 1; m >>= 1) acc += __shfl_xor(acc, m);
    if (ln == 0) score[node] = acc + b2[0];
}

// ---- softmax stats (single block) + zero gf ----
__global__ __launch_bounds__(256) void k_softmax_reduce(const float* __restrict__ score,
                                                        float* __restrict__ stats,
                                                        float* __restrict__ gf, int n)
{
    __shared__ float red[8];
    int t = threadIdx.x;
    float mx = -1e30f;
    for (int i = t; i < n; i += 256) mx = fmaxf(mx, score[i]);
#pragma unroll
    for (int m = 32; m >= 1; m >>= 1) mx = fmaxf(mx, __shfl_xor(mx, m));
    if ((t & 63) == 0) red[t >> 6] = mx;
    __syncthreads();
    mx = fmaxf(fmaxf(red[0], red[1]), fmaxf(red[2], red[3]));
    float s = 0.f;
    for (int i = t; i < n; i += 256) s += expf(score[i] - mx);
#pragma unroll
    for (int m = 32; m >= 1; m >>= 1) s += __shfl_xor(s, m);
    if ((t & 63) == 0) red[4 + (t >> 6)] = s;
    __syncthreads();
    s = red[4] + red[5] + red[6] + red[7];
    if (t == 0) { stats[0] = mx; stats[1] = s; }
    if (t < 128) gf[t] = 0.f;
}

// ---- gf = sum_n softmax(score)[n] * h[n,:] ----
__global__ __launch_bounds__(128) void k_gf(const float* __restrict__ h,
                                            const float* __restrict__ score,
                                            const float* __restrict__ stats,
                                            float* __restrict__ gf, int n)
{
    int c = threadIdx.x;
    float mx = stats[0], invZ = 1.f / stats[1];
    int per = (n + gridDim.x - 1) / gridDim.x;
    int n0 = blockIdx.x * per;
    int n1 = n0 + per; if (n1 > n) n1 = n;
    float acc = 0.f;
    for (int i = n0; i < n1; ++i)
        acc += expf(score[i] - mx) * invZ * h[(size_t)i * 128 + c];
    atomicAdd(&gf[c], acc);
}

// ---- final head (single 128-thread block) ----
__global__ __launch_bounds__(128) void k_head(
    const float* __restrict__ gf, const float* __restrict__ tf,
    const float* __restrict__ task_w, const float* __restrict__ task_b,
    const float* __restrict__ task_g, const float* __restrict__ task_be,
    const float* __restrict__ v_w1, const float* __restrict__ v_b1,
    const float* __restrict__ v_g, const float* __restrict__ v_be,
    const float* __restrict__ v_w2, const float* __restrict__ v_b2,
    const float* __restrict__ a_w1, const float* __restrict__ a_b1,
    const float* __restrict__ a_g, const float* __restrict__ a_be,
    const float* __restrict__ a_w2, const float* __restrict__ a_b2,
    float* __restrict__ out)
{
    __shared__ float cf[256], hbuf[128], red[4], sc[2], adv[10];
    int t = threadIdx.x;
    float mean, inv;
    float te = task_b[t];
#pragma unroll
    for (int k = 0; k < 4; ++k) te += tf[k] * task_w[k * 128 + t];
    ln_stats128(te, red, mean, inv);
    te = lrelu((te - mean) * inv * task_g[t] + task_be[t], 0.01f);
    cf[t] = gf[t]; cf[128 + t] = te;
    __syncthreads();
    float v = v_b1[t];
    for (int k = 0; k < 256; ++k) v += cf[k] * v_w1[k * 128 + t];
    ln_stats128(v, red, mean, inv);
    v = lrelu((v - mean) * inv * v_g[t] + v_be[t], 0.01f);
    float pv = v * v_w2[t];
#pragma unroll
    for (int m = 32; m >= 1; m >>= 1) pv += __shfl_xor(pv, m);
    __syncthreads();
    if ((t & 63) == 0) red[t >> 6] = pv;
    __syncthreads();
    if (t == 0) sc[0] = red[0] + red[1] + v_b2[0];
    float a = a_b1[t];
    for (int k = 0; k < 256; ++k) a += cf[k] * a_w1[k * 128 + t];
    ln_stats128(a, red, mean, inv);
    a = lrelu((a - mean) * inv * a_g[t] + a_be[t], 0.01f);
    hbuf[t] = a;
    __syncthreads();
    if (t < 10) {
        float s = a_b2[t];
        for (int c = 0; c < 128; ++c) s += hbuf[c] * a_w2[c * 10 + t];
        adv[t] = s;
    }
    __syncthreads();
    if (t == 0) {
        float m10 = 0.f;
        for (int o = 0; o < 10; ++o) m10 += adv[o];
        sc[1] = m10 * 0.1f;
    }
    __syncthreads();
    if (t < 10) out[t] = sc[0] + adv[t] - sc[1];
}

extern "C" void kernel_launch(void* const* d_in, const int* in_sizes, int n_in,
                              void* d_out, int out_size, void* d_ws, size_t ws_size,
                              hipStream_t stream)
{
    const float* x        = (const float*)d_in[0];
    const int*   ei       = (const int*)d_in[1];
    const float* ea       = (const float*)d_in[2];
    const float* tf       = (const float*)d_in[3];
    const float* emb_w    = (const float*)d_in[4];
    const float* emb_b    = (const float*)d_in[5];
    const float* emb_g    = (const float*)d_in[6];
    const float* emb_beta = (const float*)d_in[7];
    const float* gat_w    = (const float*)d_in[8];
    const float* gat_as   = (const float*)d_in[9];
    const float* gat_ad   = (const float*)d_in[10];
    const float* gat_bias = (const float*)d_in[11];
    const float* ec_w1    = (const float*)d_in[12];
    const float* ec_b1    = (const float*)d_in[13];
    const float* ec_g1    = (const float*)d_in[14];
    const float* ec_be1   = (const float*)d_in[15];
    const float* ec_w2    = (const float*)d_in[16];
    const float* ec_b2    = (const float*)d_in[17];
    const float* ec_g2    = (const float*)d_in[18];
    const float* ec_be2   = (const float*)d_in[19];
    const float* norm_g   = (const float*)d_in[20];
    const float* norm_b   = (const float*)d_in[21];
    const float* task_w   = (const float*)d_in[22];
    const float* task_b   = (const float*)d_in[23];
    const float* task_g   = (const float*)d_in[24];
    const float* task_be  = (const float*)d_in[25];
    const float* pa_w1    = (const float*)d_in[26];
    const float* pa_b1    = (const float*)d_in[27];
    const float* pa_w2    = (const float*)d_in[28];
    const float* pa_b2    = (const float*)d_in[29];
    const float* v_w1     = (const float*)d_in[30];
    const float* v_b1     = (const float*)d_in[31];
    const float* v_g      = (const float*)d_in[32];
    const float* v_be     = (const float*)d_in[33];
    const float* v_w2     = (const float*)d_in[34];
    const float* v_b2     = (const float*)d_in[35];
    const float* a_w1     = (const float*)d_in[36];
    const float* a_b1     = (const float*)d_in[37];
    const float* a_g      = (const float*)d_in[38];
    const float* a_be     = (const float*)d_in[39];
    const float* a_w2     = (const float*)d_in[40];
    const float* a_b2     = (const float*)d_in[41];

    const int n = in_sizes[0] / 128;   // 25000
    const int e = in_sizes[2];         // 400000
    const int* src = ei;
    const int* dst = ei + e;

    float* ws = (float*)d_ws;
    uint4* wf = (uint4*)ws;                  // 13 * 2048 uint4 = 416KB
    float* base = ws + 13 * 2048 * 4;
    const size_t NR = (size_t)n * 128;
    const size_t NP = (size_t)n * 64;
    float* h    = base;
    float* x0   = base + NR;
    float* xs   = base + 2 * NR;
    unsigned* htp = (unsigned*)(base + 3 * NR);
    unsigned* Apk = htp + NP;
    unsigned* Bpk = Apk + NP;
    float* a_s  = (float*)(Bpk + NP);
    float* a_d  = a_s + (size_t)n * 2;
    float* den  = a_d + (size_t)n * 2;
    float* selfe = den + (size_t)n * 2;
    float* rsA  = selfe + (size_t)n * 2;
    float* rsB  = rsA + n;
    float* score = rsB + n;
    float* stats = score + n;
    float* gf    = stats + 2;
    int*   cnt    = (int*)(gf + 128);
    int*   starts = cnt + n;
    int*   s_src  = starts + (n + 1);
    int*   s_dst  = s_src + e;
    float* s_ea   = (float*)(s_dst + e);
    float* expo   = s_ea + e;            // 2*E

    const int ng64 = (n + 63) / 64;
    const int ng8 = (n + 7) / 8;
    const int ngd = ((e + 7) / 8 + 255) / 256;

    // ---- one-time: counting-sort edges by dst + weight pre-pack ----
    hipMemsetAsync(cnt, 0, (size_t)n * sizeof(int), stream);
    k_hist<<<(e + 255) / 256, 256, 0, stream>>>(dst, cnt, e);
    k_scan<<<1, 1024, 0, stream>>>(cnt, starts, n);
    hipMemcpyAsync(cnt, starts, (size_t)n * sizeof(int), hipMemcpyDeviceToDevice, stream);
    k_scatter<<<(e + 255) / 256, 256, 0, stream>>>(src, dst, ea, cnt, s_src, s_dst, s_ea, e);
    k_prep<<<104, 256, 0, stream>>>(gat_w, ec_w1, ec_w2, emb_w, wf);

    // embedding: h = x0 = lrelu(LN(x @ emb_w + emb_b))
    k_emb<<<ng64, 256, 0, stream>>>(x, wf + (size_t)12 * 2048, emb_b, emb_g, emb_beta, h, x0, n);

    for (int i = 0; i < LL; ++i) {
        if (i == 0) {
            k_gemm3<<<ng64, 256, 0, stream>>>(h, nullptr, nullptr, nullptr,
                                              nullptr, nullptr, nullptr, nullptr,
                                              wf, i, 3 + 2 * i, 4 + 2 * i,
                                              ec_b1 + i * 128, htp, Apk, Bpk, n, 0);
        } else {
            // fused norm of layer i-1: reads xsum + htp(prev) + selfe/denom(prev)
            k_gemm3<<<ng64, 256, 0, stream>>>(xs, htp, selfe, den,
                                              gat_bias + (i - 1) * 128,
                                              norm_g + (i - 1) * 128, norm_b + (i - 1) * 128, x0,
                                              wf, i, 3 + 2 * i, 4 + 2 * i,
                                              ec_b1 + i * 128, htp, Apk, Bpk, n,
                                              (i == 2) ? 2 : 1);
        }
        k_node_scores<<<ng8, 512, 0, stream>>>(htp, Apk, Bpk, gat_as + i * 128, gat_ad + i * 128,
                                               a_s, a_d, den, selfe, rsA, rsB, n);
        k_edge_denom2<<<ngd, 256, 0, stream>>>(s_src, s_dst, a_s, a_d, den, expo,
                                               (float4*)xs, n * 32, e);
        k_edge_main<<<(e + EB - 1) / EB, 512, 0, stream>>>(Apk, Bpk, htp, s_src, s_dst, s_ea,
                                                           expo, den,
                                                           wf + (size_t)(9 + i) * 2048,
                                                           rsA, rsB,
                                                           ec_g1 + i * 128, ec_be1 + i * 128,
                                                           ec_b2 + i * 128, ec_g2 + i * 128, ec_be2 + i * 128,
                                                           xs, e);
    }
    // final norm (layer 2, residual) -> h for pooling
    k_norm8<<<ng8, 512, 0, stream>>>(xs, htp, selfe, den, gat_bias + 2 * 128,
                                     norm_g + 2 * 128, norm_b + 2 * 128, x0, h, n, 2);

    k_pool_score<<<(n + 3) / 4, 256, 0, stream>>>(h, pa_w1, pa_b1, pa_w2, pa_b2, score, n);
    k_softmax_reduce<<<1, 256, 0, stream>>>(score, stats, gf, n);
    k_gf<<<200, 128, 0, stream>>>(h, score, stats, gf, n);
    k_head<<<1, 128, 0, stream>>>(gf, tf, task_w, task_b, task_g, task_be,
                                  v_w1, v_b1, v_g, v_be, v_w2, v_b2,
                                  a_w1, a_b1, a_g, a_be, a_w2, a_b2,
                                  (float*)d_out);
}

// Round 14
// 697.452 us; speedup vs baseline: 1.0587x; 1.0587x over previous
//
#include <hip/hip_runtime.h>
#include <math.h>

#define NN 25000
#define EE 400000
#define LL 3
#define LNEPS 1e-5f
#define EB 64

typedef __attribute__((ext_vector_type(8))) short short8;
typedef __attribute__((ext_vector_type(16))) float f32x16;

__device__ __forceinline__ float lrelu(float x, float s) { return fmaxf(x, x * s); }

__device__ __forceinline__ unsigned int pack_bf2(float lo, float hi) {
    unsigned int ul = __float_as_uint(lo), uh = __float_as_uint(hi);
    ul = (ul + 0x7FFFu + ((ul >> 16) & 1u)) >> 16;
    uh = (uh + 0x7FFFu + ((uh >> 16) & 1u)) >> 16;
    return (uh << 16) | (ul & 0xFFFFu);
}
__device__ __forceinline__ float bf_lo(unsigned int u) { return __uint_as_float(u << 16); }
__device__ __forceinline__ float bf_hi(unsigned int u) { return __uint_as_float(u & 0xFFFF0000u); }

// 128-thread block LN stats (2 waves)
__device__ __forceinline__ void ln_stats128(float v, float* red, float& mean, float& inv) {
    float sm = v, sq = v * v;
#pragma unroll
    for (int m = 32; m >= 1; m >>= 1) { sm += __shfl_xor(sm, m); sq += __shfl_xor(sq, m); }
    __syncthreads();
    if ((threadIdx.x & 63) == 0) { red[(threadIdx.x >> 6) * 2] = sm; red[(threadIdx.x >> 6) * 2 + 1] = sq; }
    __syncthreads();
    sm = red[0] + red[2]; sq = red[1] + red[3];
    mean = sm * (1.f / 128.f);
    float var = sq * (1.f / 128.f) - mean * mean;
    inv = rsqrtf(var + LNEPS);
}

// ================= edge sorting (counting sort by dst) =================
__global__ void k_hist(const int* __restrict__ dst, int* __restrict__ cnt, int ne)
{
    int i = blockIdx.x * 256 + threadIdx.x;
    if (i < ne) atomicAdd(&cnt[dst[i]], 1);
}

__global__ __launch_bounds__(1024) void k_scan(const int* __restrict__ cnt,
                                               int* __restrict__ starts, int n)
{
    __shared__ int tot[1024];
    int t = threadIdx.x;
    const int PER = (n + 1023) >> 10;
    int i0 = t * PER;
    int s = 0;
    for (int k = 0; k < PER; ++k) { int i = i0 + k; s += (i < n) ? cnt[i] : 0; }
    tot[t] = s;
    __syncthreads();
    for (int off = 1; off < 1024; off <<= 1) {
        int x = (t >= off) ? tot[t - off] : 0;
        __syncthreads();
        tot[t] += x;
        __syncthreads();
    }
    int run = (t > 0) ? tot[t - 1] : 0;
    for (int k = 0; k < PER; ++k) {
        int i = i0 + k;
        if (i < n) { starts[i] = run; run += cnt[i]; }
    }
    if (t == 1023) starts[n] = tot[1023];
}

__global__ void k_scatter(const int* __restrict__ src, const int* __restrict__ dst,
                          const float* __restrict__ ea, int* __restrict__ cursor,
                          int* __restrict__ s_src, int* __restrict__ s_dst,
                          float* __restrict__ s_ea, int ne)
{
    int i = blockIdx.x * 256 + threadIdx.x;
    if (i >= ne) return;
    int d = dst[i];
    int pos = atomicAdd(&cursor[d], 1);
    s_src[pos] = src[i];
    s_dst[pos] = d;
    s_ea[pos] = ea[i];
}

// ================= weight pre-pack: fp32 [128x128] -> bf16 B-fragment order ====
// mat m: 0..2 gat_w[i]; 3..8 ec_w1 layer (m-3)>>1 half (m-3)&1; 9..11 ec_w2[i]; 12 emb_w
__global__ void k_prep(const float* __restrict__ gat_w, const float* __restrict__ ec_w1,
                       const float* __restrict__ ec_w2, const float* __restrict__ emb_w,
                       uint4* __restrict__ wf)
{
    int g = blockIdx.x * 256 + threadIdx.x;   // < 13*2048
    int m = g >> 11, f = g & 2047;
    const float* srcm;
    if (m < 3) srcm = gat_w + (size_t)m * 16384;
    else if (m < 9) { int t2 = m - 3; srcm = ec_w1 + (size_t)(t2 >> 1) * 32768 + (size_t)(t2 & 1) * 16384; }
    else if (m < 12) srcm = ec_w2 + (size_t)(m - 9) * 16384;
    else srcm = emb_w;
    int l = f & 63, ks = (f >> 6) & 7, nb = f >> 9;
    int k0 = ks * 16 + (l >> 5) * 8, col = nb * 32 + (l & 31);
    const float* wp = srcm + (size_t)k0 * 128 + col;
    uint4 r;
    r.x = pack_bf2(wp[0],   wp[128]);
    r.y = pack_bf2(wp[256], wp[384]);
    r.z = pack_bf2(wp[512], wp[640]);
    r.w = pack_bf2(wp[768], wp[896]);
    wf[g] = r;
}

// ---- MFMA embedding: h = x0 = lrelu(LN(x @ emb_w + emb_b)) ----
__global__ __launch_bounds__(256) void k_emb(
    const float* __restrict__ in, const uint4* __restrict__ wfm,
    const float* __restrict__ bias, const float* __restrict__ g,
    const float* __restrict__ be, float* __restrict__ h,
    float* __restrict__ x0, int nrows)
{
    __shared__ __align__(16) unsigned int sA[64 * 64];
    __shared__ __align__(16) unsigned int sW[2048 * 4];   // 32KB, reused as sU
    float* sU = (float*)sW;
    const int tid = threadIdx.x;
    const int r0 = blockIdx.x * 64;
    {
        int row = tid >> 2, q = tid & 3;
        const float* srcp = in + (size_t)(r0 + row) * 128 + q * 32;
        bool ok = (r0 + row) < nrows;
#pragma unroll
        for (int i = 0; i < 8; ++i) {
            float4 v = ok ? *(const float4*)&srcp[i * 4] : make_float4(0.f, 0.f, 0.f, 0.f);
            int cu = (q * 16 + i * 2) ^ ((row & 15) << 2);
            *(uint2*)&sA[row * 64 + cu] = make_uint2(pack_bf2(v.x, v.y), pack_bf2(v.z, v.w));
        }
    }
    {
        uint4* sW4 = (uint4*)sW;
#pragma unroll
        for (int i = 0; i < 8; ++i) sW4[tid + 256 * i] = wfm[tid + 256 * i];
    }
    __syncthreads();
    const int w = tid >> 6, l = tid & 63;
    const int m0 = (w >> 1) * 32, nhalf = (w & 1);
    f32x16 acc0 = {}, acc1 = {};
#pragma unroll
    for (int ks = 0; ks < 8; ++ks) {
        int rw = m0 + (l & 31);
        int cu = (ks * 8 + (l >> 5) * 4) ^ ((rw & 15) << 2);
        short8 a = *(const short8*)&sA[rw * 64 + cu];
        short8 b0 = *(const short8*)&sW[((nhalf * 16 + ks) * 64 + l) * 4];
        short8 b1 = *(const short8*)&sW[(((nhalf * 2 + 1) * 8 + ks) * 64 + l) * 4];
        acc0 = __builtin_amdgcn_mfma_f32_32x32x16_bf16(a, b0, acc0, 0, 0, 0);
        acc1 = __builtin_amdgcn_mfma_f32_32x32x16_bf16(a, b1, acc1, 0, 0, 0);
    }
    __syncthreads();   // all waves done reading sW
    {
        int colbase = nhalf * 64 + (l & 31);
        float bb0 = bias[colbase], bb1 = bias[colbase + 32];
#pragma unroll
        for (int r = 0; r < 16; ++r) {
            int rw = m0 + (r & 3) + 8 * (r >> 2) + 4 * (l >> 5);
            sU[rw * 128 + colbase]      = acc0[r] + bb0;
            sU[rw * 128 + colbase + 32] = acc1[r] + bb1;
        }
    }
    __syncthreads();
    // LN epilogue: 4 waves x 16 rows
    float2 gv = *(const float2*)&g[l * 2];
    float2 bv = *(const float2*)&be[l * 2];
    for (int it = 0; it < 16; ++it) {
        int rw = w * 16 + it;
        int grow = r0 + rw;
        if (grow >= nrows) break;
        float2 v = *(const float2*)&sU[rw * 128 + l * 2];
        float sm = v.x + v.y, sq = v.x * v.x + v.y * v.y;
#pragma unroll
        for (int m = 32; m >= 1; m >>= 1) { sm += __shfl_xor(sm, m); sq += __shfl_xor(sq, m); }
        float mean = sm * (1.f / 128.f);
        float var = sq * (1.f / 128.f) - mean * mean;
        float inv = rsqrtf(var + LNEPS);
        float o0 = lrelu((v.x - mean) * inv * gv.x + bv.x, 0.01f);
        float o1 = lrelu((v.y - mean) * inv * gv.y + bv.y, 0.01f);
        unsigned off = (unsigned)grow * 128u + (unsigned)(l * 2);
        *(float2*)&h[off]  = make_float2(o0, o1);
        *(float2*)&x0[off] = make_float2(o0, o1);
    }
}

// ---- MFMA 3-in-1 node GEMM: {ht, A'(+b1), B} = act @ {Wht, WA, WB}, packed bf16 out.
//      mode 0: act = in (fp32 h rows).
//      mode 1: act = lrelu(LN(xsum + gbias + selfloop))            (fused k_norm8, no residual)
//      mode 2: ... + x0 residual, x0 updated                        (fused k_norm8, residual)
__global__ __launch_bounds__(256) void k_gemm3(
    const float* __restrict__ in, const unsigned* __restrict__ htp_in,
    const float* __restrict__ selfe, const float* __restrict__ denom,
    const float* __restrict__ gbias, const float* __restrict__ ng,
    const float* __restrict__ nb, float* __restrict__ x0,
    const uint4* __restrict__ wf,
    int mht, int mA, int mB, const float* __restrict__ bA,
    unsigned* __restrict__ o0, unsigned* __restrict__ o1, unsigned* __restrict__ o2,
    int nrows, int mode)
{
    __shared__ __align__(16) unsigned int sA[64 * 64];     // 16KB bf16 tile, XOR-swizzled
    __shared__ __align__(16) unsigned int sW[2048 * 4];    // 32KB B-fragments
    const int tid = threadIdx.x;
    const int r0 = blockIdx.x * 64;
    {
        int row = tid >> 2, q = tid & 3;
        int node = r0 + row;
        bool ok = node < nrows;
        if (mode == 0) {
            const float* srcp = in + (size_t)node * 128 + q * 32;
#pragma unroll
            for (int i = 0; i < 8; ++i) {
                float4 v = ok ? *(const float4*)&srcp[i * 4] : make_float4(0.f, 0.f, 0.f, 0.f);
                int cu = (q * 16 + i * 2) ^ ((row & 15) << 2);
                *(uint2*)&sA[row * 64 + cu] = make_uint2(pack_bf2(v.x, v.y), pack_bf2(v.z, v.w));
            }
        } else {
            // fused norm of previous layer: LN(xsum + gbias + ht_prev*alpha) (+x0)
            unsigned off128 = (unsigned)node * 128u + (unsigned)(q * 32);
            unsigned off64  = (unsigned)node * 64u + (unsigned)(q * 16);
            int hd = q >> 1;
            float alpha = ok ? (selfe[node * 2 + hd] / denom[node * 2 + hd]) : 0.f;
            float4 vv[8];
            float sm = 0.f, sq = 0.f;
#pragma unroll
            for (int i = 0; i < 8; ++i) {
                float4 v = ok ? *(const float4*)&in[off128 + i * 4] : make_float4(0.f, 0.f, 0.f, 0.f);
                uint2 hvp = ok ? *(const uint2*)&htp_in[off64 + i * 2] : make_uint2(0u, 0u);
                float4 gbv = *(const float4*)&gbias[q * 32 + i * 4];
                v.x += gbv.x + bf_lo(hvp.x) * alpha;
                v.y += gbv.y + bf_hi(hvp.x) * alpha;
                v.z += gbv.z + bf_lo(hvp.y) * alpha;
                v.w += gbv.w + bf_hi(hvp.y) * alpha;
                vv[i] = v;
                sm += v.x + v.y + v.z + v.w;
                sq += v.x * v.x + v.y * v.y + v.z * v.z + v.w * v.w;
            }
            sm += __shfl_xor(sm, 1); sq += __shfl_xor(sq, 1);
            sm += __shfl_xor(sm, 2); sq += __shfl_xor(sq, 2);
            float mean = sm * (1.f / 128.f);
            float inv = rsqrtf(sq * (1.f / 128.f) - mean * mean + LNEPS);
#pragma unroll
            for (int i = 0; i < 8; ++i) {
                float4 v = vv[i];
                float4 gv = *(const float4*)&ng[q * 32 + i * 4];
                float4 bv = *(const float4*)&nb[q * 32 + i * 4];
                float w0 = lrelu((v.x - mean) * inv * gv.x + bv.x, 0.01f);
                float w1 = lrelu((v.y - mean) * inv * gv.y + bv.y, 0.01f);
                float w2 = lrelu((v.z - mean) * inv * gv.z + bv.z, 0.01f);
                float w3 = lrelu((v.w - mean) * inv * gv.w + bv.w, 0.01f);
                if (mode == 2 && ok) {
                    float4 xv = *(const float4*)&x0[off128 + i * 4];
                    w0 += xv.x; w1 += xv.y; w2 += xv.z; w3 += xv.w;
                    *(float4*)&x0[off128 + i * 4] = make_float4(w0, w1, w2, w3);
                }
                int cu = (q * 16 + i * 2) ^ ((row & 15) << 2);
                *(uint2*)&sA[row * 64 + cu] = make_uint2(pack_bf2(w0, w1), pack_bf2(w2, w3));
            }
        }
    }
    __syncthreads();
    const int w = tid >> 6, l = tid & 63;
    const int m0 = (w >> 1) * 32, nhalf = (w & 1);
    short8 af[8];
#pragma unroll
    for (int ks = 0; ks < 8; ++ks) {
        int row = m0 + (l & 31);
        int cu = (ks * 8 + (l >> 5) * 4) ^ ((row & 15) << 2);
        af[ks] = *(const short8*)&sA[row * 64 + cu];
    }
    const int c = l & 31;
    const bool evenl = (c & 1) == 0;
    const unsigned uidx = (unsigned)(nhalf * 32 + (evenl ? (c >> 1) : (16 + (c >> 1))));
    auto do_mat = [&](int mat, unsigned* out, const float* bp) {
        __syncthreads();
        {
            const uint4* wsrc = wf + (size_t)mat * 2048;
            uint4* sW4 = (uint4*)sW;
#pragma unroll
            for (int i = 0; i < 8; ++i) sW4[tid + 256 * i] = wsrc[tid + 256 * i];
        }
        __syncthreads();
        f32x16 acc0 = {}, acc1 = {};
        const int nb0 = nhalf * 2;
#pragma unroll
        for (int ks = 0; ks < 8; ++ks) {
            short8 b0 = *(const short8*)&sW[((nb0 * 8 + ks) * 64 + l) * 4];
            short8 b1v = *(const short8*)&sW[(((nb0 + 1) * 8 + ks) * 64 + l) * 4];
            acc0 = __builtin_amdgcn_mfma_f32_32x32x16_bf16(af[ks], b0, acc0, 0, 0, 0);
            acc1 = __builtin_amdgcn_mfma_f32_32x32x16_bf16(af[ks], b1v, acc1, 0, 0, 0);
        }
        int colbase = nhalf * 64 + c;
        float badd0 = bp ? bp[colbase] : 0.f;
        float badd1 = bp ? bp[colbase + 32] : 0.f;
#pragma unroll
        for (int r = 0; r < 16; ++r) {
            float v0 = acc0[r] + badd0;
            float v1 = acc1[r] + badd1;
            float v0p = __shfl_xor(v0, 1);
            float v1p = __shfl_xor(v1, 1);
            int row = r0 + m0 + (r & 3) + 8 * (r >> 2) + 4 * (l >> 5);
            if (row < nrows) {
                unsigned val = evenl ? pack_bf2(v0, v0p) : pack_bf2(v1p, v1);
                out[(unsigned)row * 64u + uidx] = val;
            }
        }
    };
    do_mat(mht, o0, nullptr);
    do_mat(mA, o1, bA);
    do_mat(mB, o2, nullptr);
}

// ---- merged per-node pass: GAT scores + selfe/denom init + row sums of A',B ----
__global__ __launch_bounds__(512) void k_node_scores(
    const unsigned* __restrict__ htp, const unsigned* __restrict__ Apk,
    const unsigned* __restrict__ Bpk,
    const float* __restrict__ as_, const float* __restrict__ ad_,
    float* __restrict__ a_s, float* __restrict__ a_d,
    float* __restrict__ denom, float* __restrict__ selfe,
    float* __restrict__ rsA, float* __restrict__ rsB, int n)
{
    int wv = threadIdx.x >> 6, ln = threadIdx.x & 63;
    int node = blockIdx.x * 8 + wv;
    if (node >= n) return;
    unsigned off = (unsigned)node * 64u + (unsigned)ln;
    unsigned hv = htp[off], av = Apk[off], bv = Bpk[off];
    float h0 = bf_lo(hv), h1 = bf_hi(hv);
    float2 wsv = *(const float2*)&as_[ln * 2];
    float2 wdv = *(const float2*)&ad_[ln * 2];
    float ss = h0 * wsv.x + h1 * wsv.y;
    float sd = h0 * wdv.x + h1 * wdv.y;
    float sa = bf_lo(av) + bf_hi(av), sb = bf_lo(bv) + bf_hi(bv);
#pragma unroll
    for (int m = 16; m >= 1; m >>= 1) {
        ss += __shfl_xor(ss, m); sd += __shfl_xor(sd, m);
        sa += __shfl_xor(sa, m); sb += __shfl_xor(sb, m);
    }
    float sa2 = sa + __shfl_xor(sa, 32);
    float sb2 = sb + __shfl_xor(sb, 32);
    if ((ln & 31) == 0) {
        int hd = ln >> 5;
        a_s[node * 2 + hd] = ss;
        a_d[node * 2 + hd] = sd;
        float ev = expf(lrelu(ss + sd, 0.2f));
        denom[node * 2 + hd] = ev;
        selfe[node * 2 + hd] = ev;
        if (hd == 0) { rsA[node] = sa2; rsB[node] = sb2; }
    }
}

// ---- accumulate exp(e) per dst over sorted edges (run-merged), store expo, zero xsum ----
__global__ void k_edge_denom2(const int* __restrict__ s_src, const int* __restrict__ s_dst,
                              const float* __restrict__ a_s, const float* __restrict__ a_d,
                              float* __restrict__ denom, float* __restrict__ expo,
                              float4* __restrict__ xz, int nz4, int ne)
{
    int gtid = blockIdx.x * 256 + threadIdx.x;
    for (int i = gtid; i < nz4; i += gridDim.x * 256)
        xz[i] = make_float4(0.f, 0.f, 0.f, 0.f);
    int base = gtid * 8;
    if (base >= ne) return;
    int curd = -1;
    float acc0 = 0.f, acc1 = 0.f;
    for (int k = 0; k < 8; ++k) {
        int e = base + k;
        if (e >= ne) break;
        int s = s_src[e], d = s_dst[e];
        float v0 = expf(lrelu(a_s[(unsigned)(s * 2)]     + a_d[(unsigned)(d * 2)],     0.2f));
        float v1 = expf(lrelu(a_s[(unsigned)(s * 2 + 1)] + a_d[(unsigned)(d * 2 + 1)], 0.2f));
        *(float2*)&expo[(unsigned)e * 2] = make_float2(v0, v1);
        if (d != curd) {
            if (curd >= 0) { atomicAdd(&denom[curd * 2], acc0); atomicAdd(&denom[curd * 2 + 1], acc1); }
            curd = d; acc0 = v0; acc1 = v1;
        } else { acc0 += v0; acc1 += v1; }
    }
    if (curd >= 0) { atomicAdd(&denom[curd * 2], acc0); atomicAdd(&denom[curd * 2 + 1], acc1); }
}

// ---- fused edge kernel (dst-sorted): EdgeConv MLP (MFMA) + GAT, run-merged scatter.
//      LDS diet v2: NO W2 staging (B-fragments read from L2-resident global wf);
//      u stored packed bf16 overlaying sT32. LDS ~21.5KB -> 4 blocks/CU.
__global__ __launch_bounds__(512) void k_edge_main(
    const unsigned* __restrict__ Apk, const unsigned* __restrict__ Bpk,
    const unsigned* __restrict__ htp,
    const int* __restrict__ s_src, const int* __restrict__ s_dst,
    const float* __restrict__ s_ea,
    const float* __restrict__ expo, const float* __restrict__ denom,
    const uint4* __restrict__ w2f,
    const float* __restrict__ rsA, const float* __restrict__ rsB,
    const float* __restrict__ g1, const float* __restrict__ be1,
    const float* __restrict__ b2, const float* __restrict__ g2, const float* __restrict__ be2,
    float* __restrict__ xsum, int ne)
{
    __shared__ __align__(16) unsigned int sT32[EB * 64];   // t tile bf16 pairs; reused as packed u
    __shared__ int   sS[EB], sD[EB];
    __shared__ float sEA[EB], sM[EB];
    __shared__ float sAl[EB * 2];
    __shared__ float sMean[EB], sInv[EB];
    __shared__ float sG1[128], sE1[128], sB2[128], sG2[128], sE2[128];
    unsigned* sUp = sT32;   // packed bf16 u-tile [64][64] uints, after phase-2 barrier

    const int tid = threadIdx.x;
    if (tid < 128) {
        sG1[tid] = g1[tid]; sE1[tid] = be1[tid];
        sB2[tid] = b2[tid]; sG2[tid] = g2[tid]; sE2[tid] = be2[tid];
    }
    const int e0 = blockIdx.x * EB;
    const int nev = (ne - e0 < EB) ? (ne - e0) : EB;
    if (tid < EB) {
        if (tid < nev) {
            int s = s_src[e0 + tid], d = s_dst[e0 + tid];
            sS[tid] = s; sD[tid] = d; sEA[tid] = s_ea[e0 + tid];
            sM[tid] = (rsA[s] + rsB[d]) * (1.f / 128.f);
        } else { sS[tid] = 0; sD[tid] = -1; sEA[tid] = 0.f; sM[tid] = 0.f; }
    }
    if (tid < 2 * EB) {
        int le = tid >> 1, hd = tid & 1;
        float al = 0.f;
        if (le < nev) {
            int e = e0 + le;
            int d = s_dst[e];
            al = expo[(unsigned)e * 2 + hd] / denom[(unsigned)(d * 2 + hd)];
        }
        sAl[le * 2 + hd] = al;
    }
    __syncthreads();

    const int wv = tid >> 6, ln = tid & 63;
    const int half = ln >> 5, lc = ln & 31;

    // phase 1 (pair-mode): lanes 0-31 -> edge 2j, lanes 32-63 -> edge 2j+1.
    {
        const float g10 = sG1[lc * 4], g11 = sG1[lc * 4 + 1], g12 = sG1[lc * 4 + 2], g13 = sG1[lc * 4 + 3];
        const float e10 = sE1[lc * 4], e11 = sE1[lc * 4 + 1], e12 = sE1[lc * 4 + 2], e13 = sE1[lc * 4 + 3];
        for (int j = 0; j < 4; ++j) {
            int e = wv * 8 + j * 2 + half;
            if (e < nev) {
                unsigned s = (unsigned)sS[e], d = (unsigned)sD[e];
                float mean = sM[e];
                uint2 av = *(const uint2*)&Apk[s * 64u + (unsigned)(lc * 2)];
                uint2 bv = *(const uint2*)&Bpk[d * 64u + (unsigned)(lc * 2)];
                float v0 = bf_lo(av.x) + bf_lo(bv.x) - mean;
                float v1 = bf_hi(av.x) + bf_hi(bv.x) - mean;
                float v2 = bf_lo(av.y) + bf_lo(bv.y) - mean;
                float v3 = bf_hi(av.y) + bf_hi(bv.y) - mean;
                float sq = v0 * v0 + v1 * v1 + v2 * v2 + v3 * v3;
#pragma unroll
                for (int m = 16; m >= 1; m >>= 1) sq += __shfl_xor(sq, m);
                float inv = rsqrtf(sq * (1.f / 128.f) + LNEPS);
                float t0 = lrelu(v0 * inv * g10 + e10, 0.2f);
                float t1 = lrelu(v1 * inv * g11 + e11, 0.2f);
                float t2 = lrelu(v2 * inv * g12 + e12, 0.2f);
                float t3 = lrelu(v3 * inv * g13 + e13, 0.2f);
                int cu = (lc * 2) ^ ((e & 15) << 2);
                *(uint2*)&sT32[e * 64 + cu] = make_uint2(pack_bf2(t0, t1), pack_bf2(t2, t3));
            }
        }
    }
    __syncthreads();

    // phase 2: u = t @ W2 via MFMA; B-fragments straight from global (L2-hit).
    // After the barrier, sT32 is reused as the packed bf16 u-tile (sUp).
    {
        const int w = wv, l = ln;
        const int m0 = (w >> 2) * 32, n0 = (w & 3) * 32;
        f32x16 acc = {};
#pragma unroll
        for (int ks = 0; ks < 8; ++ks) {
            int row = m0 + (l & 31);
            int colu = (ks * 8 + (l >> 5) * 4) ^ ((row & 15) << 2);
            short8 a = *(const short8*)&sT32[row * 64 + colu];
            short8 b = *(const short8*)&w2f[(((w & 3) * 8 + ks) * 64 + l)];
            acc = __builtin_amdgcn_mfma_f32_32x32x16_bf16(a, b, acc, 0, 0, 0);
        }
        __syncthreads();   // all waves done reading sT32 before overwriting as sUp
        const int c = l & 31;
        float b2c = sB2[n0 + c];
        const bool evenc = (c & 1) == 0;
        const unsigned ubase = (unsigned)((w & 3) * 16 + (c >> 1));
#pragma unroll
        for (int r = 0; r < 16; ++r) {
            float v = acc[r] + b2c;
            float vp = __shfl_xor(v, 1);
            if (evenc) {
                int row = m0 + (r & 3) + 8 * (r >> 2) + 4 * (l >> 5);
                sUp[(unsigned)row * 64u + ubase] = pack_bf2(v, vp);
            }
        }
    }
    __syncthreads();

    // phase 2.5 (pair-mode stats): each wave computes mean/inv for its own 8 edges.
    for (int j = 0; j < 4; ++j) {
        int e = wv * 8 + j * 2 + half;
        if (e < nev) {
            uint2 up = *(const uint2*)&sUp[(unsigned)e * 64u + (unsigned)(lc * 2)];
            float u0 = bf_lo(up.x), u1 = bf_hi(up.x), u2 = bf_lo(up.y), u3 = bf_hi(up.y);
            float sm = u0 + u1 + u2 + u3;
            float sq = u0 * u0 + u1 * u1 + u2 * u2 + u3 * u3;
#pragma unroll
            for (int m = 16; m >= 1; m >>= 1) { sm += __shfl_xor(sm, m); sq += __shfl_xor(sq, m); }
            if (lc == 0) {
                float mean = sm * (1.f / 128.f);
                sMean[e] = mean;
                sInv[e] = rsqrtf(sq * (1.f / 128.f) - mean * mean + LNEPS);
            }
        }
    }

    // phase 3: LN(u)+lrelu (stats from LDS), *edge_attr, + GAT ht[src]*alpha;
    // run-merged atomic scatter (64-lane per edge, 8-edge merge window)
    {
        const unsigned ln2 = (unsigned)(ln * 2);
        const float g2a = sG2[ln * 2], g2b = sG2[ln * 2 + 1];
        const float e2a = sE2[ln * 2], e2b = sE2[ln * 2 + 1];
        int curd = -1;
        float acc0 = 0.f, acc1 = 0.f;
        for (int j = 0; j < 8; ++j) {
            int e = wv * 8 + j;
            if (e >= nev) break;
            unsigned s = (unsigned)sS[e];
            int d = sD[e];
            float mean = sMean[e], inv = sInv[e];
            unsigned up = sUp[(unsigned)e * 64u + (unsigned)ln];
            float eav = sEA[e];
            float v0 = lrelu((bf_lo(up) - mean) * inv * g2a + e2a, 0.2f) * eav;
            float v1 = lrelu((bf_hi(up) - mean) * inv * g2b + e2b, 0.2f) * eav;
            float al = sAl[e * 2 + half];
            unsigned hv = htp[s * 64u + ln];
            v0 += bf_lo(hv) * al;
            v1 += bf_hi(hv) * al;
            if (d != curd) {
                if (curd >= 0) {
                    atomicAdd(&xsum[(unsigned)curd * 128u + ln2], acc0);
                    atomicAdd(&xsum[(unsigned)curd * 128u + ln2 + 1], acc1);
                }
                curd = d; acc0 = v0; acc1 = v1;
            } else { acc0 += v0; acc1 += v1; }
        }
        if (curd >= 0) {
            atomicAdd(&xsum[(unsigned)curd * 128u + ln2], acc0);
            atomicAdd(&xsum[(unsigned)curd * 128u + ln2 + 1], acc1);
        }
    }
}

// ---- h = lrelu(LN(xsum + gat_bias + selfloop)) (+ x0 residual), wave-per-node ----
__global__ __launch_bounds__(512) void k_norm8(const float* __restrict__ xsum,
                                               const unsigned* __restrict__ htp,
                                               const float* __restrict__ selfe,
                                               const float* __restrict__ denom,
                                               const float* __restrict__ gbias,
                                               const float* __restrict__ g,
                                               const float* __restrict__ b,
                                               float* __restrict__ x0,
                                               float* __restrict__ h, int n, int layer)
{
    int wv = threadIdx.x >> 6, ln = threadIdx.x & 63;
    int node = blockIdx.x * 8 + wv;
    if (node >= n) return;
    unsigned off = (unsigned)node * 128u + (unsigned)(ln * 2);
    int hd = ln >> 5;
    float alpha = selfe[node * 2 + hd] / denom[node * 2 + hd];
    unsigned hv = htp[(unsigned)node * 64u + (unsigned)ln];
    float2 gb = *(const float2*)&gbias[ln * 2];
    float2 v = *(const float2*)&xsum[off];
    v.x += gb.x + bf_lo(hv) * alpha;
    v.y += gb.y + bf_hi(hv) * alpha;
    float sm = v.x + v.y, sq = v.x * v.x + v.y * v.y;
#pragma unroll
    for (int m = 32; m >= 1; m >>= 1) { sm += __shfl_xor(sm, m); sq += __shfl_xor(sq, m); }
    float mean = sm * (1.f / 128.f);
    float var = sq * (1.f / 128.f) - mean * mean;
    float inv = rsqrtf(var + LNEPS);
    float2 gv = *(const float2*)&g[ln * 2];
    float2 bv = *(const float2*)&b[ln * 2];
    float val0 = lrelu((v.x - mean) * inv * gv.x + bv.x, 0.01f);
    float val1 = lrelu((v.y - mean) * inv * gv.y + bv.y, 0.01f);
    if (layer > 0) {
        float2 x0v = *(const float2*)&x0[off];
        val0 += x0v.x; val1 += x0v.y;
        *(float2*)&x0[off] = make_float2(val0, val1);
    }
    *(float2*)&h[off] = make_float2(val0, val1);
}

// ---- pooling attention scores (one node per wave) ----
__global__ __launch_bounds__(256) void k_pool_score(const float* __restrict__ h,
    const float* __restrict__ w1, const float* __restrict__ b1,
    const float* __restrict__ w2, const float* __restrict__ b2,
    float* __restrict__ score, int n)
{
    int wv = threadIdx.x >> 6, ln = threadIdx.x & 63;
    int node = blockIdx.x * 4 + wv;
    if (node >= n) return;
    float acc = b1[ln];
    const float* hr = h + (size_t)node * 128;
    for (int k = 0; k < 128; ++k) acc += hr[k] * w1[k * 64 + ln];
    acc = lrelu(acc, 0.01f) * w2[ln];
#pragma unroll
    for (int m = 32; m >= 1; m >>= 1) acc += __shfl_xor(acc, m);
    if (ln == 0) score[node] = acc + b2[0];
}

// ---- softmax stats (single block) + zero gf ----
__global__ __launch_bounds__(256) void k_softmax_reduce(const float* __restrict__ score,
                                                        float* __restrict__ stats,
                                                        float* __restrict__ gf, int n)
{
    __shared__ float red[8];
    int t = threadIdx.x;
    float mx = -1e30f;
    for (int i = t; i < n; i += 256) mx = fmaxf(mx, score[i]);
#pragma unroll
    for (int m = 32; m >= 1; m >>= 1) mx = fmaxf(mx, __shfl_xor(mx, m));
    if ((t & 63) == 0) red[t >> 6] = mx;
    __syncthreads();
    mx = fmaxf(fmaxf(red[0], red[1]), fmaxf(red[2], red[3]));
    float s = 0.f;
    for (int i = t; i < n; i += 256) s += expf(score[i] - mx);
#pragma unroll
    for (int m = 32; m >= 1; m >>= 1) s += __shfl_xor(s, m);
    if ((t & 63) == 0) red[4 + (t >> 6)] = s;
    __syncthreads();
    s = red[4] + red[5] + red[6] + red[7];
    if (t == 0) { stats[0] = mx; stats[1] = s; }
    if (t < 128) gf[t] = 0.f;
}

// ---- gf = sum_n softmax(score)[n] * h[n,:] ----
__global__ __launch_bounds__(128) void k_gf(const float* __restrict__ h,
                                            const float* __restrict__ score,
                                            const float* __restrict__ stats,
                                            float* __restrict__ gf, int n)
{
    int c = threadIdx.x;
    float mx = stats[0], invZ = 1.f / stats[1];
    int per = (n + gridDim.x - 1) / gridDim.x;
    int n0 = blockIdx.x * per;
    int n1 = n0 + per; if (n1 > n) n1 = n;
    float acc = 0.f;
    for (int i = n0; i < n1; ++i)
        acc += expf(score[i] - mx) * invZ * h[(size_t)i * 128 + c];
    atomicAdd(&gf[c], acc);
}

// ---- final head (single 128-thread block) ----
__global__ __launch_bounds__(128) void k_head(
    const float* __restrict__ gf, const float* __restrict__ tf,
    const float* __restrict__ task_w, const float* __restrict__ task_b,
    const float* __restrict__ task_g, const float* __restrict__ task_be,
    const float* __restrict__ v_w1, const float* __restrict__ v_b1,
    const float* __restrict__ v_g, const float* __restrict__ v_be,
    const float* __restrict__ v_w2, const float* __restrict__ v_b2,
    const float* __restrict__ a_w1, const float* __restrict__ a_b1,
    const float* __restrict__ a_g, const float* __restrict__ a_be,
    const float* __restrict__ a_w2, const float* __restrict__ a_b2,
    float* __restrict__ out)
{
    __shared__ float cf[256], hbuf[128], red[4], sc[2], adv[10];
    int t = threadIdx.x;
    float mean, inv;
    float te = task_b[t];
#pragma unroll
    for (int k = 0; k < 4; ++k) te += tf[k] * task_w[k * 128 + t];
    ln_stats128(te, red, mean, inv);
    te = lrelu((te - mean) * inv * task_g[t] + task_be[t], 0.01f);
    cf[t] = gf[t]; cf[128 + t] = te;
    __syncthreads();
    float v = v_b1[t];
    for (int k = 0; k < 256; ++k) v += cf[k] * v_w1[k * 128 + t];
    ln_stats128(v, red, mean, inv);
    v = lrelu((v - mean) * inv * v_g[t] + v_be[t], 0.01f);
    float pv = v * v_w2[t];
#pragma unroll
    for (int m = 32; m >= 1; m >>= 1) pv += __shfl_xor(pv, m);
    __syncthreads();
    if ((t & 63) == 0) red[t >> 6] = pv;
    __syncthreads();
    if (t == 0) sc[0] = red[0] + red[1] + v_b2[0];
    float a = a_b1[t];
    for (int k = 0; k < 256; ++k) a += cf[k] * a_w1[k * 128 + t];
    ln_stats128(a, red, mean, inv);
    a = lrelu((a - mean) * inv * a_g[t] + a_be[t], 0.01f);
    hbuf[t] = a;
    __syncthreads();
    if (t < 10) {
        float s = a_b2[t];
        for (int c = 0; c < 128; ++c) s += hbuf[c] * a_w2[c * 10 + t];
        adv[t] = s;
    }
    __syncthreads();
    if (t == 0) {
        float m10 = 0.f;
        for (int o = 0; o < 10; ++o) m10 += adv[o];
        sc[1] = m10 * 0.1f;
    }
    __syncthreads();
    if (t < 10) out[t] = sc[0] + adv[t] - sc[1];
}

extern "C" void kernel_launch(void* const* d_in, const int* in_sizes, int n_in,
                              void* d_out, int out_size, void* d_ws, size_t ws_size,
                              hipStream_t stream)
{
    const float* x        = (const float*)d_in[0];
    const int*   ei       = (const int*)d_in[1];
    const float* ea       = (const float*)d_in[2];
    const float* tf       = (const float*)d_in[3];
    const float* emb_w    = (const float*)d_in[4];
    const float* emb_b    = (const float*)d_in[5];
    const float* emb_g    = (const float*)d_in[6];
    const float* emb_beta = (const float*)d_in[7];
    const float* gat_w    = (const float*)d_in[8];
    const float* gat_as   = (const float*)d_in[9];
    const float* gat_ad   = (const float*)d_in[10];
    const float* gat_bias = (const float*)d_in[11];
    const float* ec_w1    = (const float*)d_in[12];
    const float* ec_b1    = (const float*)d_in[13];
    const float* ec_g1    = (const float*)d_in[14];
    const float* ec_be1   = (const float*)d_in[15];
    const float* ec_w2    = (const float*)d_in[16];
    const float* ec_b2    = (const float*)d_in[17];
    const float* ec_g2    = (const float*)d_in[18];
    const float* ec_be2   = (const float*)d_in[19];
    const float* norm_g   = (const float*)d_in[20];
    const float* norm_b   = (const float*)d_in[21];
    const float* task_w   = (const float*)d_in[22];
    const float* task_b   = (const float*)d_in[23];
    const float* task_g   = (const float*)d_in[24];
    const float* task_be  = (const float*)d_in[25];
    const float* pa_w1    = (const float*)d_in[26];
    const float* pa_b1    = (const float*)d_in[27];
    const float* pa_w2    = (const float*)d_in[28];
    const float* pa_b2    = (const float*)d_in[29];
    const float* v_w1     = (const float*)d_in[30];
    const float* v_b1     = (const float*)d_in[31];
    const float* v_g      = (const float*)d_in[32];
    const float* v_be     = (const float*)d_in[33];
    const float* v_w2     = (const float*)d_in[34];
    const float* v_b2     = (const float*)d_in[35];
    const float* a_w1     = (const float*)d_in[36];
    const float* a_b1     = (const float*)d_in[37];
    const float* a_g      = (const float*)d_in[38];
    const float* a_be     = (const float*)d_in[39];
    const float* a_w2     = (const float*)d_in[40];
    const float* a_b2     = (const float*)d_in[41];

    const int n = in_sizes[0] / 128;   // 25000
    const int e = in_sizes[2];         // 400000
    const int* src = ei;
    const int* dst = ei + e;

    float* ws = (float*)d_ws;
    uint4* wf = (uint4*)ws;                  // 13 * 2048 uint4 = 416KB
    float* base = ws + 13 * 2048 * 4;
    const size_t NR = (size_t)n * 128;
    const size_t NP = (size_t)n * 64;
    float* h    = base;
    float* x0   = base + NR;
    float* xs   = base + 2 * NR;
    unsigned* htp = (unsigned*)(base + 3 * NR);
    unsigned* Apk = htp + NP;
    unsigned* Bpk = Apk + NP;
    float* a_s  = (float*)(Bpk + NP);
    float* a_d  = a_s + (size_t)n * 2;
    float* den  = a_d + (size_t)n * 2;
    float* selfe = den + (size_t)n * 2;
    float* rsA  = selfe + (size_t)n * 2;
    float* rsB  = rsA + n;
    float* score = rsB + n;
    float* stats = score + n;
    float* gf    = stats + 2;
    int*   cnt    = (int*)(gf + 128);
    int*   starts = cnt + n;
    int*   s_src  = starts + (n + 1);
    int*   s_dst  = s_src + e;
    float* s_ea   = (float*)(s_dst + e);
    float* expo   = s_ea + e;            // 2*E

    const int ng64 = (n + 63) / 64;
    const int ng8 = (n + 7) / 8;
    const int ngd = ((e + 7) / 8 + 255) / 256;

    // ---- one-time: counting-sort edges by dst + weight pre-pack ----
    hipMemsetAsync(cnt, 0, (size_t)n * sizeof(int), stream);
    k_hist<<<(e + 255) / 256, 256, 0, stream>>>(dst, cnt, e);
    k_scan<<<1, 1024, 0, stream>>>(cnt, starts, n);
    hipMemcpyAsync(cnt, starts, (size_t)n * sizeof(int), hipMemcpyDeviceToDevice, stream);
    k_scatter<<<(e + 255) / 256, 256, 0, stream>>>(src, dst, ea, cnt, s_src, s_dst, s_ea, e);
    k_prep<<<104, 256, 0, stream>>>(gat_w, ec_w1, ec_w2, emb_w, wf);

    // embedding: h = x0 = lrelu(LN(x @ emb_w + emb_b))
    k_emb<<<ng64, 256, 0, stream>>>(x, wf + (size_t)12 * 2048, emb_b, emb_g, emb_beta, h, x0, n);

    for (int i = 0; i < LL; ++i) {
        if (i == 0) {
            k_gemm3<<<ng64, 256, 0, stream>>>(h, nullptr, nullptr, nullptr,
                                              nullptr, nullptr, nullptr, nullptr,
                                              wf, i, 3 + 2 * i, 4 + 2 * i,
                                              ec_b1 + i * 128, htp, Apk, Bpk, n, 0);
        } else {
            // fused norm of layer i-1: reads xsum + htp(prev) + selfe/denom(prev)
            k_gemm3<<<ng64, 256, 0, stream>>>(xs, htp, selfe, den,
                                              gat_bias + (i - 1) * 128,
                                              norm_g + (i - 1) * 128, norm_b + (i - 1) * 128, x0,
                                              wf, i, 3 + 2 * i, 4 + 2 * i,
                                              ec_b1 + i * 128, htp, Apk, Bpk, n,
                                              (i == 2) ? 2 : 1);
        }
        k_node_scores<<<ng8, 512, 0, stream>>>(htp, Apk, Bpk, gat_as + i * 128, gat_ad + i * 128,
                                               a_s, a_d, den, selfe, rsA, rsB, n);
        k_edge_denom2<<<ngd, 256, 0, stream>>>(s_src, s_dst, a_s, a_d, den, expo,
                                               (float4*)xs, n * 32, e);
        k_edge_main<<<(e + EB - 1) / EB, 512, 0, stream>>>(Apk, Bpk, htp, s_src, s_dst, s_ea,
                                                           expo, den,
                                                           wf + (size_t)(9 + i) * 2048,
                                                           rsA, rsB,
                                                           ec_g1 + i * 128, ec_be1 + i * 128,
                                                           ec_b2 + i * 128, ec_g2 + i * 128, ec_be2 + i * 128,
                                                           xs, e);
    }
    // final norm (layer 2, residual) -> h for pooling
    k_norm8<<<ng8, 512, 0, stream>>>(xs, htp, selfe, den, gat_bias + 2 * 128,
                                     norm_g + 2 * 128, norm_b + 2 * 128, x0, h, n, 2);

    k_pool_score<<<(n + 3) / 4, 256, 0, stream>>>(h, pa_w1, pa_b1, pa_w2, pa_b2, score, n);
    k_softmax_reduce<<<1, 256, 0, stream>>>(score, stats, gf, n);
    k_gf<<<200, 128, 0, stream>>>(h, score, stats, gf, n);
    k_head<<<1, 128, 0, stream>>>(gf, tf, task_w, task_b, task_g, task_be,
                                  v_w1, v_b1, v_g, v_be, v_w2, v_b2,
                                  a_w1, a_b1, a_g, a_be, a_w2, a_b2,
                                  (float*)d_out);
}

// Round 15
// 661.535 us; speedup vs baseline: 1.1162x; 1.0543x over previous
//
#include <hip/hip_runtime.h>
#include <math.h>

#define NN 25000
#define EE 400000
#define LL 3
#define LNEPS 1e-5f
#define EB 64

typedef __attribute__((ext_vector_type(8))) short short8;
typedef __attribute__((ext_vector_type(16))) float f32x16;

__device__ __forceinline__ float lrelu(float x, float s) { return fmaxf(x, x * s); }

__device__ __forceinline__ unsigned int pack_bf2(float lo, float hi) {
    unsigned int ul = __float_as_uint(lo), uh = __float_as_uint(hi);
    ul = (ul + 0x7FFFu + ((ul >> 16) & 1u)) >> 16;
    uh = (uh + 0x7FFFu + ((uh >> 16) & 1u)) >> 16;
    return (uh << 16) | (ul & 0xFFFFu);
}
__device__ __forceinline__ float bf_lo(unsigned int u) { return __uint_as_float(u << 16); }
__device__ __forceinline__ float bf_hi(unsigned int u) { return __uint_as_float(u & 0xFFFF0000u); }

// 128-thread block LN stats (2 waves)
__device__ __forceinline__ void ln_stats128(float v, float* red, float& mean, float& inv) {
    float sm = v, sq = v * v;
#pragma unroll
    for (int m = 32; m >= 1; m >>= 1) { sm += __shfl_xor(sm, m); sq += __shfl_xor(sq, m); }
    __syncthreads();
    if ((threadIdx.x & 63) == 0) { red[(threadIdx.x >> 6) * 2] = sm; red[(threadIdx.x >> 6) * 2 + 1] = sq; }
    __syncthreads();
    sm = red[0] + red[2]; sq = red[1] + red[3];
    mean = sm * (1.f / 128.f);
    float var = sq * (1.f / 128.f) - mean * mean;
    inv = rsqrtf(var + LNEPS);
}

// ================= edge sorting (counting sort by dst) =================
__global__ void k_hist(const int* __restrict__ dst, int* __restrict__ cnt, int ne)
{
    int i = blockIdx.x * 256 + threadIdx.x;
    if (i < ne) atomicAdd(&cnt[dst[i]], 1);
}

__global__ __launch_bounds__(1024) void k_scan(const int* __restrict__ cnt,
                                               int* __restrict__ starts, int n)
{
    __shared__ int tot[1024];
    int t = threadIdx.x;
    const int PER = (n + 1023) >> 10;
    int i0 = t * PER;
    int s = 0;
    for (int k = 0; k < PER; ++k) { int i = i0 + k; s += (i < n) ? cnt[i] : 0; }
    tot[t] = s;
    __syncthreads();
    for (int off = 1; off < 1024; off <<= 1) {
        int x = (t >= off) ? tot[t - off] : 0;
        __syncthreads();
        tot[t] += x;
        __syncthreads();
    }
    int run = (t > 0) ? tot[t - 1] : 0;
    for (int k = 0; k < PER; ++k) {
        int i = i0 + k;
        if (i < n) { starts[i] = run; run += cnt[i]; }
    }
    if (t == 1023) starts[n] = tot[1023];
}

__global__ void k_scatter(const int* __restrict__ src, const int* __restrict__ dst,
                          const float* __restrict__ ea, int* __restrict__ cursor,
                          int* __restrict__ s_src, int* __restrict__ s_dst,
                          float* __restrict__ s_ea, int ne)
{
    int i = blockIdx.x * 256 + threadIdx.x;
    if (i >= ne) return;
    int d = dst[i];
    int pos = atomicAdd(&cursor[d], 1);
    s_src[pos] = src[i];
    s_dst[pos] = d;
    s_ea[pos] = ea[i];
}

// ================= weight pre-pack: fp32 -> bf16 B-fragment order ====
// mat m: 0..2 gat_w[i]; 3..8 ec_w1 layer (m-3)>>1 half (m-3)&1; 9..11 ec_w2[i]; 12 emb_w
// g in [13*2048, 13*2048+1024): pa_w1 [128x64] (row stride 64), cols 0..63
__global__ void k_prep(const float* __restrict__ gat_w, const float* __restrict__ ec_w1,
                       const float* __restrict__ ec_w2, const float* __restrict__ emb_w,
                       const float* __restrict__ pa_w1, uint4* __restrict__ wf)
{
    int g = blockIdx.x * 256 + threadIdx.x;   // < 13*2048 + 1024
    if (g < 13 * 2048) {
        int m = g >> 11, f = g & 2047;
        const float* srcm;
        if (m < 3) srcm = gat_w + (size_t)m * 16384;
        else if (m < 9) { int t2 = m - 3; srcm = ec_w1 + (size_t)(t2 >> 1) * 32768 + (size_t)(t2 & 1) * 16384; }
        else if (m < 12) srcm = ec_w2 + (size_t)(m - 9) * 16384;
        else srcm = emb_w;
        int l = f & 63, ks = (f >> 6) & 7, nb = f >> 9;
        int k0 = ks * 16 + (l >> 5) * 8, col = nb * 32 + (l & 31);
        const float* wp = srcm + (size_t)k0 * 128 + col;
        uint4 r;
        r.x = pack_bf2(wp[0],   wp[128]);
        r.y = pack_bf2(wp[256], wp[384]);
        r.z = pack_bf2(wp[512], wp[640]);
        r.w = pack_bf2(wp[768], wp[896]);
        wf[g] = r;
    } else if (g < 13 * 2048 + 1024) {
        int f = g - 13 * 2048;
        int l = f & 63, ks = (f >> 6) & 7, nb = f >> 9;   // nb in {0,1}
        int k0 = ks * 16 + (l >> 5) * 8, col = nb * 32 + (l & 31);
        const float* wp = pa_w1 + (size_t)k0 * 64 + col;
        uint4 r;
        r.x = pack_bf2(wp[0],   wp[64]);
        r.y = pack_bf2(wp[128], wp[192]);
        r.z = pack_bf2(wp[256], wp[320]);
        r.w = pack_bf2(wp[384], wp[448]);
        wf[g] = r;
    }
}

// ---- MFMA embedding: h = x0 = lrelu(LN(x @ emb_w + emb_b)) ----
__global__ __launch_bounds__(256) void k_emb(
    const float* __restrict__ in, const uint4* __restrict__ wfm,
    const float* __restrict__ bias, const float* __restrict__ g,
    const float* __restrict__ be, float* __restrict__ h,
    float* __restrict__ x0, int nrows)
{
    __shared__ __align__(16) unsigned int sA[64 * 64];
    __shared__ __align__(16) unsigned int sW[2048 * 4];   // 32KB, reused as sU
    float* sU = (float*)sW;
    const int tid = threadIdx.x;
    const int r0 = blockIdx.x * 64;
    {
        int row = tid >> 2, q = tid & 3;
        const float* srcp = in + (size_t)(r0 + row) * 128 + q * 32;
        bool ok = (r0 + row) < nrows;
#pragma unroll
        for (int i = 0; i < 8; ++i) {
            float4 v = ok ? *(const float4*)&srcp[i * 4] : make_float4(0.f, 0.f, 0.f, 0.f);
            int cu = (q * 16 + i * 2) ^ ((row & 15) << 2);
            *(uint2*)&sA[row * 64 + cu] = make_uint2(pack_bf2(v.x, v.y), pack_bf2(v.z, v.w));
        }
    }
    {
        uint4* sW4 = (uint4*)sW;
#pragma unroll
        for (int i = 0; i < 8; ++i) sW4[tid + 256 * i] = wfm[tid + 256 * i];
    }
    __syncthreads();
    const int w = tid >> 6, l = tid & 63;
    const int m0 = (w >> 1) * 32, nhalf = (w & 1);
    f32x16 acc0 = {}, acc1 = {};
#pragma unroll
    for (int ks = 0; ks < 8; ++ks) {
        int rw = m0 + (l & 31);
        int cu = (ks * 8 + (l >> 5) * 4) ^ ((rw & 15) << 2);
        short8 a = *(const short8*)&sA[rw * 64 + cu];
        short8 b0 = *(const short8*)&sW[((nhalf * 16 + ks) * 64 + l) * 4];
        short8 b1 = *(const short8*)&sW[(((nhalf * 2 + 1) * 8 + ks) * 64 + l) * 4];
        acc0 = __builtin_amdgcn_mfma_f32_32x32x16_bf16(a, b0, acc0, 0, 0, 0);
        acc1 = __builtin_amdgcn_mfma_f32_32x32x16_bf16(a, b1, acc1, 0, 0, 0);
    }
    __syncthreads();   // all waves done reading sW
    {
        int colbase = nhalf * 64 + (l & 31);
        float bb0 = bias[colbase], bb1 = bias[colbase + 32];
#pragma unroll
        for (int r = 0; r < 16; ++r) {
            int rw = m0 + (r & 3) + 8 * (r >> 2) + 4 * (l >> 5);
            sU[rw * 128 + colbase]      = acc0[r] + bb0;
            sU[rw * 128 + colbase + 32] = acc1[r] + bb1;
        }
    }
    __syncthreads();
    // LN epilogue: 4 waves x 16 rows
    float2 gv = *(const float2*)&g[l * 2];
    float2 bv = *(const float2*)&be[l * 2];
    for (int it = 0; it < 16; ++it) {
        int rw = w * 16 + it;
        int grow = r0 + rw;
        if (grow >= nrows) break;
        float2 v = *(const float2*)&sU[rw * 128 + l * 2];
        float sm = v.x + v.y, sq = v.x * v.x + v.y * v.y;
#pragma unroll
        for (int m = 32; m >= 1; m >>= 1) { sm += __shfl_xor(sm, m); sq += __shfl_xor(sq, m); }
        float mean = sm * (1.f / 128.f);
        float var = sq * (1.f / 128.f) - mean * mean;
        float inv = rsqrtf(var + LNEPS);
        float o0 = lrelu((v.x - mean) * inv * gv.x + bv.x, 0.01f);
        float o1 = lrelu((v.y - mean) * inv * gv.y + bv.y, 0.01f);
        unsigned off = (unsigned)grow * 128u + (unsigned)(l * 2);
        *(float2*)&h[off]  = make_float2(o0, o1);
        *(float2*)&x0[off] = make_float2(o0, o1);
    }
}

// ---- MFMA 3-in-1 node GEMM: {ht, A'(+b1), B} = act @ {Wht, WA, WB}, packed bf16 out.
//      mode 0: act = in (fp32 h rows).
//      mode 1: act = lrelu(LN(xsum + gbias + selfloop))            (fused k_norm8, no residual)
//      mode 2: ... + x0 residual, x0 updated                        (fused k_norm8, residual)
__global__ __launch_bounds__(256) void k_gemm3(
    const float* __restrict__ in, const unsigned* __restrict__ htp_in,
    const float* __restrict__ selfe, const float* __restrict__ denom,
    const float* __restrict__ gbias, const float* __restrict__ ng,
    const float* __restrict__ nb, float* __restrict__ x0,
    const uint4* __restrict__ wf,
    int mht, int mA, int mB, const float* __restrict__ bA,
    unsigned* __restrict__ o0, unsigned* __restrict__ o1, unsigned* __restrict__ o2,
    int nrows, int mode)
{
    __shared__ __align__(16) unsigned int sA[64 * 64];     // 16KB bf16 tile, XOR-swizzled
    __shared__ __align__(16) unsigned int sW[2048 * 4];    // 32KB B-fragments
    const int tid = threadIdx.x;
    const int r0 = blockIdx.x * 64;
    {
        int row = tid >> 2, q = tid & 3;
        int node = r0 + row;
        bool ok = node < nrows;
        if (mode == 0) {
            const float* srcp = in + (size_t)node * 128 + q * 32;
#pragma unroll
            for (int i = 0; i < 8; ++i) {
                float4 v = ok ? *(const float4*)&srcp[i * 4] : make_float4(0.f, 0.f, 0.f, 0.f);
                int cu = (q * 16 + i * 2) ^ ((row & 15) << 2);
                *(uint2*)&sA[row * 64 + cu] = make_uint2(pack_bf2(v.x, v.y), pack_bf2(v.z, v.w));
            }
        } else {
            // fused norm of previous layer: LN(xsum + gbias + ht_prev*alpha) (+x0)
            unsigned off128 = (unsigned)node * 128u + (unsigned)(q * 32);
            unsigned off64  = (unsigned)node * 64u + (unsigned)(q * 16);
            int hd = q >> 1;
            float alpha = ok ? (selfe[node * 2 + hd] / denom[node * 2 + hd]) : 0.f;
            float4 vv[8];
            float sm = 0.f, sq = 0.f;
#pragma unroll
            for (int i = 0; i < 8; ++i) {
                float4 v = ok ? *(const float4*)&in[off128 + i * 4] : make_float4(0.f, 0.f, 0.f, 0.f);
                uint2 hvp = ok ? *(const uint2*)&htp_in[off64 + i * 2] : make_uint2(0u, 0u);
                float4 gbv = *(const float4*)&gbias[q * 32 + i * 4];
                v.x += gbv.x + bf_lo(hvp.x) * alpha;
                v.y += gbv.y + bf_hi(hvp.x) * alpha;
                v.z += gbv.z + bf_lo(hvp.y) * alpha;
                v.w += gbv.w + bf_hi(hvp.y) * alpha;
                vv[i] = v;
                sm += v.x + v.y + v.z + v.w;
                sq += v.x * v.x + v.y * v.y + v.z * v.z + v.w * v.w;
            }
            sm += __shfl_xor(sm, 1); sq += __shfl_xor(sq, 1);
            sm += __shfl_xor(sm, 2); sq += __shfl_xor(sq, 2);
            float mean = sm * (1.f / 128.f);
            float inv = rsqrtf(sq * (1.f / 128.f) - mean * mean + LNEPS);
#pragma unroll
            for (int i = 0; i < 8; ++i) {
                float4 v = vv[i];
                float4 gv = *(const float4*)&ng[q * 32 + i * 4];
                float4 bv = *(const float4*)&nb[q * 32 + i * 4];
                float w0 = lrelu((v.x - mean) * inv * gv.x + bv.x, 0.01f);
                float w1 = lrelu((v.y - mean) * inv * gv.y + bv.y, 0.01f);
                float w2 = lrelu((v.z - mean) * inv * gv.z + bv.z, 0.01f);
                float w3 = lrelu((v.w - mean) * inv * gv.w + bv.w, 0.01f);
                if (mode == 2 && ok) {
                    float4 xv = *(const float4*)&x0[off128 + i * 4];
                    w0 += xv.x; w1 += xv.y; w2 += xv.z; w3 += xv.w;
                    *(float4*)&x0[off128 + i * 4] = make_float4(w0, w1, w2, w3);
                }
                int cu = (q * 16 + i * 2) ^ ((row & 15) << 2);
                *(uint2*)&sA[row * 64 + cu] = make_uint2(pack_bf2(w0, w1), pack_bf2(w2, w3));
            }
        }
    }
    __syncthreads();
    const int w = tid >> 6, l = tid & 63;
    const int m0 = (w >> 1) * 32, nhalf = (w & 1);
    short8 af[8];
#pragma unroll
    for (int ks = 0; ks < 8; ++ks) {
        int row = m0 + (l & 31);
        int cu = (ks * 8 + (l >> 5) * 4) ^ ((row & 15) << 2);
        af[ks] = *(const short8*)&sA[row * 64 + cu];
    }
    const int c = l & 31;
    const bool evenl = (c & 1) == 0;
    const unsigned uidx = (unsigned)(nhalf * 32 + (evenl ? (c >> 1) : (16 + (c >> 1))));
    auto do_mat = [&](int mat, unsigned* out, const float* bp) {
        __syncthreads();
        {
            const uint4* wsrc = wf + (size_t)mat * 2048;
            uint4* sW4 = (uint4*)sW;
#pragma unroll
            for (int i = 0; i < 8; ++i) sW4[tid + 256 * i] = wsrc[tid + 256 * i];
        }
        __syncthreads();
        f32x16 acc0 = {}, acc1 = {};
        const int nb0 = nhalf * 2;
#pragma unroll
        for (int ks = 0; ks < 8; ++ks) {
            short8 b0 = *(const short8*)&sW[((nb0 * 8 + ks) * 64 + l) * 4];
            short8 b1v = *(const short8*)&sW[(((nb0 + 1) * 8 + ks) * 64 + l) * 4];
            acc0 = __builtin_amdgcn_mfma_f32_32x32x16_bf16(af[ks], b0, acc0, 0, 0, 0);
            acc1 = __builtin_amdgcn_mfma_f32_32x32x16_bf16(af[ks], b1v, acc1, 0, 0, 0);
        }
        int colbase = nhalf * 64 + c;
        float badd0 = bp ? bp[colbase] : 0.f;
        float badd1 = bp ? bp[colbase + 32] : 0.f;
#pragma unroll
        for (int r = 0; r < 16; ++r) {
            float v0 = acc0[r] + badd0;
            float v1 = acc1[r] + badd1;
            float v0p = __shfl_xor(v0, 1);
            float v1p = __shfl_xor(v1, 1);
            int row = r0 + m0 + (r & 3) + 8 * (r >> 2) + 4 * (l >> 5);
            if (row < nrows) {
                unsigned val = evenl ? pack_bf2(v0, v0p) : pack_bf2(v1p, v1);
                out[(unsigned)row * 64u + uidx] = val;
            }
        }
    };
    do_mat(mht, o0, nullptr);
    do_mat(mA, o1, bA);
    do_mat(mB, o2, nullptr);
}

// ---- merged per-node pass: GAT scores + selfe/denom init + row sums of A',B ----
__global__ __launch_bounds__(512) void k_node_scores(
    const unsigned* __restrict__ htp, const unsigned* __restrict__ Apk,
    const unsigned* __restrict__ Bpk,
    const float* __restrict__ as_, const float* __restrict__ ad_,
    float* __restrict__ a_s, float* __restrict__ a_d,
    float* __restrict__ denom, float* __restrict__ selfe,
    float* __restrict__ rsA, float* __restrict__ rsB, int n)
{
    int wv = threadIdx.x >> 6, ln = threadIdx.x & 63;
    int node = blockIdx.x * 8 + wv;
    if (node >= n) return;
    unsigned off = (unsigned)node * 64u + (unsigned)ln;
    unsigned hv = htp[off], av = Apk[off], bv = Bpk[off];
    float h0 = bf_lo(hv), h1 = bf_hi(hv);
    float2 wsv = *(const float2*)&as_[ln * 2];
    float2 wdv = *(const float2*)&ad_[ln * 2];
    float ss = h0 * wsv.x + h1 * wsv.y;
    float sd = h0 * wdv.x + h1 * wdv.y;
    float sa = bf_lo(av) + bf_hi(av), sb = bf_lo(bv) + bf_hi(bv);
#pragma unroll
    for (int m = 16; m >= 1; m >>= 1) {
        ss += __shfl_xor(ss, m); sd += __shfl_xor(sd, m);
        sa += __shfl_xor(sa, m); sb += __shfl_xor(sb, m);
    }
    float sa2 = sa + __shfl_xor(sa, 32);
    float sb2 = sb + __shfl_xor(sb, 32);
    if ((ln & 31) == 0) {
        int hd = ln >> 5;
        a_s[node * 2 + hd] = ss;
        a_d[node * 2 + hd] = sd;
        float ev = expf(lrelu(ss + sd, 0.2f));
        denom[node * 2 + hd] = ev;
        selfe[node * 2 + hd] = ev;
        if (hd == 0) { rsA[node] = sa2; rsB[node] = sb2; }
    }
}

// ---- accumulate exp(e) per dst over sorted edges (run-merged), store expo, zero xsum ----
__global__ void k_edge_denom2(const int* __restrict__ s_src, const int* __restrict__ s_dst,
                              const float* __restrict__ a_s, const float* __restrict__ a_d,
                              float* __restrict__ denom, float* __restrict__ expo,
                              float4* __restrict__ xz, int nz4, int ne)
{
    int gtid = blockIdx.x * 256 + threadIdx.x;
    for (int i = gtid; i < nz4; i += gridDim.x * 256)
        xz[i] = make_float4(0.f, 0.f, 0.f, 0.f);
    int base = gtid * 8;
    if (base >= ne) return;
    int curd = -1;
    float acc0 = 0.f, acc1 = 0.f;
    for (int k = 0; k < 8; ++k) {
        int e = base + k;
        if (e >= ne) break;
        int s = s_src[e], d = s_dst[e];
        float v0 = expf(lrelu(a_s[(unsigned)(s * 2)]     + a_d[(unsigned)(d * 2)],     0.2f));
        float v1 = expf(lrelu(a_s[(unsigned)(s * 2 + 1)] + a_d[(unsigned)(d * 2 + 1)], 0.2f));
        *(float2*)&expo[(unsigned)e * 2] = make_float2(v0, v1);
        if (d != curd) {
            if (curd >= 0) { atomicAdd(&denom[curd * 2], acc0); atomicAdd(&denom[curd * 2 + 1], acc1); }
            curd = d; acc0 = v0; acc1 = v1;
        } else { acc0 += v0; acc1 += v1; }
    }
    if (curd >= 0) { atomicAdd(&denom[curd * 2], acc0); atomicAdd(&denom[curd * 2 + 1], acc1); }
}

// ---- fused edge kernel (dst-sorted): EdgeConv MLP (MFMA) + GAT, run-merged scatter.
//      LDS diet v2: NO W2 staging (B-fragments read from L2-resident global wf);
//      u stored packed bf16 overlaying sT32. LDS ~21KB -> 4 blocks/CU.
__global__ __launch_bounds__(512) void k_edge_main(
    const unsigned* __restrict__ Apk, const unsigned* __restrict__ Bpk,
    const unsigned* __restrict__ htp,
    const int* __restrict__ s_src, const int* __restrict__ s_dst,
    const float* __restrict__ s_ea,
    const float* __restrict__ expo, const float* __restrict__ denom,
    const uint4* __restrict__ w2f,
    const float* __restrict__ rsA, const float* __restrict__ rsB,
    const float* __restrict__ g1, const float* __restrict__ be1,
    const float* __restrict__ b2, const float* __restrict__ g2, const float* __restrict__ be2,
    float* __restrict__ xsum, int ne)
{
    __shared__ __align__(16) unsigned int sT32[EB * 64];   // t tile bf16 pairs; reused as packed u
    __shared__ int   sS[EB], sD[EB];
    __shared__ float sEA[EB], sM[EB];
    __shared__ float sAl[EB * 2];
    __shared__ float sMean[EB], sInv[EB];
    __shared__ float sG1[128], sE1[128], sB2[128], sG2[128], sE2[128];
    unsigned* sUp = sT32;   // packed bf16 u-tile [64][64] uints, after phase-2 barrier

    const int tid = threadIdx.x;
    if (tid < 128) {
        sG1[tid] = g1[tid]; sE1[tid] = be1[tid];
        sB2[tid] = b2[tid]; sG2[tid] = g2[tid]; sE2[tid] = be2[tid];
    }
    const int e0 = blockIdx.x * EB;
    const int nev = (ne - e0 < EB) ? (ne - e0) : EB;
    if (tid < EB) {
        if (tid < nev) {
            int s = s_src[e0 + tid], d = s_dst[e0 + tid];
            sS[tid] = s; sD[tid] = d; sEA[tid] = s_ea[e0 + tid];
            sM[tid] = (rsA[s] + rsB[d]) * (1.f / 128.f);
        } else { sS[tid] = 0; sD[tid] = -1; sEA[tid] = 0.f; sM[tid] = 0.f; }
    }
    if (tid < 2 * EB) {
        int le = tid >> 1, hd = tid & 1;
        float al = 0.f;
        if (le < nev) {
            int e = e0 + le;
            int d = s_dst[e];
            al = expo[(unsigned)e * 2 + hd] / denom[(unsigned)(d * 2 + hd)];
        }
        sAl[le * 2 + hd] = al;
    }
    __syncthreads();

    const int wv = tid >> 6, ln = tid & 63;
    const int half = ln >> 5, lc = ln & 31;

    // phase 1 (pair-mode): lanes 0-31 -> edge 2j, lanes 32-63 -> edge 2j+1.
    {
        const float g10 = sG1[lc * 4], g11 = sG1[lc * 4 + 1], g12 = sG1[lc * 4 + 2], g13 = sG1[lc * 4 + 3];
        const float e10 = sE1[lc * 4], e11 = sE1[lc * 4 + 1], e12 = sE1[lc * 4 + 2], e13 = sE1[lc * 4 + 3];
        for (int j = 0; j < 4; ++j) {
            int e = wv * 8 + j * 2 + half;
            if (e < nev) {
                unsigned s = (unsigned)sS[e], d = (unsigned)sD[e];
                float mean = sM[e];
                uint2 av = *(const uint2*)&Apk[s * 64u + (unsigned)(lc * 2)];
                uint2 bv = *(const uint2*)&Bpk[d * 64u + (unsigned)(lc * 2)];
                float v0 = bf_lo(av.x) + bf_lo(bv.x) - mean;
                float v1 = bf_hi(av.x) + bf_hi(bv.x) - mean;
                float v2 = bf_lo(av.y) + bf_lo(bv.y) - mean;
                float v3 = bf_hi(av.y) + bf_hi(bv.y) - mean;
                float sq = v0 * v0 + v1 * v1 + v2 * v2 + v3 * v3;
#pragma unroll
                for (int m = 16; m >= 1; m >>= 1) sq += __shfl_xor(sq, m);
                float inv = rsqrtf(sq * (1.f / 128.f) + LNEPS);
                float t0 = lrelu(v0 * inv * g10 + e10, 0.2f);
                float t1 = lrelu(v1 * inv * g11 + e11, 0.2f);
                float t2 = lrelu(v2 * inv * g12 + e12, 0.2f);
                float t3 = lrelu(v3 * inv * g13 + e13, 0.2f);
                int cu = (lc * 2) ^ ((e & 15) << 2);
                *(uint2*)&sT32[e * 64 + cu] = make_uint2(pack_bf2(t0, t1), pack_bf2(t2, t3));
            }
        }
    }
    __syncthreads();

    // phase 2: u = t @ W2 via MFMA; B-fragments straight from global (L2-hit).
    {
        const int w = wv, l = ln;
        const int m0 = (w >> 2) * 32, n0 = (w & 3) * 32;
        f32x16 acc = {};
#pragma unroll
        for (int ks = 0; ks < 8; ++ks) {
            int row = m0 + (l & 31);
            int colu = (ks * 8 + (l >> 5) * 4) ^ ((row & 15) << 2);
            short8 a = *(const short8*)&sT32[row * 64 + colu];
            short8 b = *(const short8*)&w2f[(((w & 3) * 8 + ks) * 64 + l)];
            acc = __builtin_amdgcn_mfma_f32_32x32x16_bf16(a, b, acc, 0, 0, 0);
        }
        __syncthreads();   // all waves done reading sT32 before overwriting as sUp
        const int c = l & 31;
        float b2c = sB2[n0 + c];
        const bool evenc = (c & 1) == 0;
        const unsigned ubase = (unsigned)((w & 3) * 16 + (c >> 1));
#pragma unroll
        for (int r = 0; r < 16; ++r) {
            float v = acc[r] + b2c;
            float vp = __shfl_xor(v, 1);
            if (evenc) {
                int row = m0 + (r & 3) + 8 * (r >> 2) + 4 * (l >> 5);
                sUp[(unsigned)row * 64u + ubase] = pack_bf2(v, vp);
            }
        }
    }
    __syncthreads();

    // phase 2.5 (pair-mode stats): each wave computes mean/inv for its own 8 edges.
    for (int j = 0; j < 4; ++j) {
        int e = wv * 8 + j * 2 + half;
        if (e < nev) {
            uint2 up = *(const uint2*)&sUp[(unsigned)e * 64u + (unsigned)(lc * 2)];
            float u0 = bf_lo(up.x), u1 = bf_hi(up.x), u2 = bf_lo(up.y), u3 = bf_hi(up.y);
            float sm = u0 + u1 + u2 + u3;
            float sq = u0 * u0 + u1 * u1 + u2 * u2 + u3 * u3;
#pragma unroll
            for (int m = 16; m >= 1; m >>= 1) { sm += __shfl_xor(sm, m); sq += __shfl_xor(sq, m); }
            if (lc == 0) {
                float mean = sm * (1.f / 128.f);
                sMean[e] = mean;
                sInv[e] = rsqrtf(sq * (1.f / 128.f) - mean * mean + LNEPS);
            }
        }
    }

    // phase 3: LN(u)+lrelu (stats from LDS), *edge_attr, + GAT ht[src]*alpha;
    // run-merged atomic scatter (64-lane per edge, 8-edge merge window)
    {
        const unsigned ln2 = (unsigned)(ln * 2);
        const float g2a = sG2[ln * 2], g2b = sG2[ln * 2 + 1];
        const float e2a = sE2[ln * 2], e2b = sE2[ln * 2 + 1];
        int curd = -1;
        float acc0 = 0.f, acc1 = 0.f;
        for (int j = 0; j < 8; ++j) {
            int e = wv * 8 + j;
            if (e >= nev) break;
            unsigned s = (unsigned)sS[e];
            int d = sD[e];
            float mean = sMean[e], inv = sInv[e];
            unsigned up = sUp[(unsigned)e * 64u + (unsigned)ln];
            float eav = sEA[e];
            float v0 = lrelu((bf_lo(up) - mean) * inv * g2a + e2a, 0.2f) * eav;
            float v1 = lrelu((bf_hi(up) - mean) * inv * g2b + e2b, 0.2f) * eav;
            float al = sAl[e * 2 + half];
            unsigned hv = htp[s * 64u + ln];
            v0 += bf_lo(hv) * al;
            v1 += bf_hi(hv) * al;
            if (d != curd) {
                if (curd >= 0) {
                    atomicAdd(&xsum[(unsigned)curd * 128u + ln2], acc0);
                    atomicAdd(&xsum[(unsigned)curd * 128u + ln2 + 1], acc1);
                }
                curd = d; acc0 = v0; acc1 = v1;
            } else { acc0 += v0; acc1 += v1; }
        }
        if (curd >= 0) {
            atomicAdd(&xsum[(unsigned)curd * 128u + ln2], acc0);
            atomicAdd(&xsum[(unsigned)curd * 128u + ln2 + 1], acc1);
        }
    }
}

// ---- h = lrelu(LN(xsum + gat_bias + selfloop)) (+ x0 residual), wave-per-node ----
__global__ __launch_bounds__(512) void k_norm8(const float* __restrict__ xsum,
                                               const unsigned* __restrict__ htp,
                                               const float* __restrict__ selfe,
                                               const float* __restrict__ denom,
                                               const float* __restrict__ gbias,
                                               const float* __restrict__ g,
                                               const float* __restrict__ b,
                                               float* __restrict__ x0,
                                               float* __restrict__ h, int n, int layer)
{
    int wv = threadIdx.x >> 6, ln = threadIdx.x & 63;
    int node = blockIdx.x * 8 + wv;
    if (node >= n) return;
    unsigned off = (unsigned)node * 128u + (unsigned)(ln * 2);
    int hd = ln >> 5;
    float alpha = selfe[node * 2 + hd] / denom[node * 2 + hd];
    unsigned hv = htp[(unsigned)node * 64u + (unsigned)ln];
    float2 gb = *(const float2*)&gbias[ln * 2];
    float2 v = *(const float2*)&xsum[off];
    v.x += gb.x + bf_lo(hv) * alpha;
    v.y += gb.y + bf_hi(hv) * alpha;
    float sm = v.x + v.y, sq = v.x * v.x + v.y * v.y;
#pragma unroll
    for (int m = 32; m >= 1; m >>= 1) { sm += __shfl_xor(sm, m); sq += __shfl_xor(sq, m); }
    float mean = sm * (1.f / 128.f);
    float var = sq * (1.f / 128.f) - mean * mean;
    float inv = rsqrtf(var + LNEPS);
    float2 gv = *(const float2*)&g[ln * 2];
    float2 bv = *(const float2*)&b[ln * 2];
    float val0 = lrelu((v.x - mean) * inv * gv.x + bv.x, 0.01f);
    float val1 = lrelu((v.y - mean) * inv * gv.y + bv.y, 0.01f);
    if (layer > 0) {
        float2 x0v = *(const float2*)&x0[off];
        val0 += x0v.x; val1 += x0v.y;
        *(float2*)&x0[off] = make_float2(val0, val1);
    }
    *(float2*)&h[off] = make_float2(val0, val1);
}

// ---- MFMA pooling scores: score = lrelu(h @ pa_w1 + b1) @ pa_w2 + b2 ----
__global__ __launch_bounds__(256) void k_pool(
    const float* __restrict__ h, const uint4* __restrict__ wfp,
    const float* __restrict__ b1, const float* __restrict__ w2,
    const float* __restrict__ b2, float* __restrict__ score, int nrows)
{
    __shared__ __align__(16) unsigned int sA[64 * 64];   // 16KB h tile
    __shared__ __align__(16) unsigned int sW[1024 * 4];  // 16KB pa_w1 fragments
    __shared__ float sPart[64][2];
    const int tid = threadIdx.x;
    const int r0 = blockIdx.x * 64;
    {
        int row = tid >> 2, q = tid & 3;
        const float* srcp = h + (size_t)(r0 + row) * 128 + q * 32;
        bool ok = (r0 + row) < nrows;
#pragma unroll
        for (int i = 0; i < 8; ++i) {
            float4 v = ok ? *(const float4*)&srcp[i * 4] : make_float4(0.f, 0.f, 0.f, 0.f);
            int cu = (q * 16 + i * 2) ^ ((row & 15) << 2);
            *(uint2*)&sA[row * 64 + cu] = make_uint2(pack_bf2(v.x, v.y), pack_bf2(v.z, v.w));
        }
    }
    {
        uint4* sW4 = (uint4*)sW;
#pragma unroll
        for (int i = 0; i < 4; ++i) sW4[tid + 256 * i] = wfp[tid + 256 * i];
    }
    __syncthreads();
    const int w = tid >> 6, l = tid & 63;
    const int m0 = (w >> 1) * 32, nb = (w & 1);
    const int c = l & 31;
    f32x16 acc = {};
#pragma unroll
    for (int ks = 0; ks < 8; ++ks) {
        int row = m0 + c;
        int cu = (ks * 8 + (l >> 5) * 4) ^ ((row & 15) << 2);
        short8 a = *(const short8*)&sA[row * 64 + cu];
        short8 b = *(const short8*)&sW[((nb * 8 + ks) * 64 + l) * 4];
        acc = __builtin_amdgcn_mfma_f32_32x32x16_bf16(a, b, acc, 0, 0, 0);
    }
    int col = nb * 32 + c;
    float b1c = b1[col], w2c = w2[col];
#pragma unroll
    for (int r = 0; r < 16; ++r) {
        float p = lrelu(acc[r] + b1c, 0.01f) * w2c;
#pragma unroll
        for (int m = 16; m >= 1; m >>= 1) p += __shfl_xor(p, m);
        if (c == 0) {
            int row = m0 + (r & 3) + 8 * (r >> 2) + 4 * (l >> 5);
            sPart[row][nb] = p;
        }
    }
    __syncthreads();
    if (tid < 64) {
        int grow = r0 + tid;
        if (grow < nrows) score[grow] = sPart[tid][0] + sPart[tid][1] + b2[0];
    }
}

// ---- softmax stats (single block) + zero gf ----
__global__ __launch_bounds__(256) void k_softmax_reduce(const float* __restrict__ score,
                                                        float* __restrict__ stats,
                                                        float* __restrict__ gf, int n)
{
    __shared__ float red[8];
    int t = threadIdx.x;
    float mx = -1e30f;
    for (int i = t; i < n; i += 256) mx = fmaxf(mx, score[i]);
#pragma unroll
    for (int m = 32; m >= 1; m >>= 1) mx = fmaxf(mx, __shfl_xor(mx, m));
    if ((t & 63) == 0) red[t >> 6] = mx;
    __syncthreads();
    mx = fmaxf(fmaxf(red[0], red[1]), fmaxf(red[2], red[3]));
    float s = 0.f;
    for (int i = t; i < n; i += 256) s += expf(score[i] - mx);
#pragma unroll
    for (int m = 32; m >= 1; m >>= 1) s += __shfl_xor(s, m);
    if ((t & 63) == 0) red[4 + (t >> 6)] = s;
    __syncthreads();
    s = red[4] + red[5] + red[6] + red[7];
    if (t == 0) { stats[0] = mx; stats[1] = s; }
    if (t < 128) gf[t] = 0.f;
}

// ---- gf = sum_n softmax(score)[n] * h[n,:] ----
__global__ __launch_bounds__(128) void k_gf(const float* __restrict__ h,
                                            const float* __restrict__ score,
                                            const float* __restrict__ stats,
                                            float* __restrict__ gf, int n)
{
    int c = threadIdx.x;
    float mx = stats[0], invZ = 1.f / stats[1];
    int per = (n + gridDim.x - 1) / gridDim.x;
    int n0 = blockIdx.x * per;
    int n1 = n0 + per; if (n1 > n) n1 = n;
    float acc = 0.f;
    for (int i = n0; i < n1; ++i)
        acc += expf(score[i] - mx) * invZ * h[(size_t)i * 128 + c];
    atomicAdd(&gf[c], acc);
}

// ---- final head (single 128-thread block) ----
__global__ __launch_bounds__(128) void k_head(
    const float* __restrict__ gf, const float* __restrict__ tf,
    const float* __restrict__ task_w, const float* __restrict__ task_b,
    const float* __restrict__ task_g, const float* __restrict__ task_be,
    const float* __restrict__ v_w1, const float* __restrict__ v_b1,
    const float* __restrict__ v_g, const float* __restrict__ v_be,
    const float* __restrict__ v_w2, const float* __restrict__ v_b2,
    const float* __restrict__ a_w1, const float* __restrict__ a_b1,
    const float* __restrict__ a_g, const float* __restrict__ a_be,
    const float* __restrict__ a_w2, const float* __restrict__ a_b2,
    float* __restrict__ out)
{
    __shared__ float cf[256], hbuf[128], red[4], sc[2], adv[10];
    int t = threadIdx.x;
    float mean, inv;
    float te = task_b[t];
#pragma unroll
    for (int k = 0; k < 4; ++k) te += tf[k] * task_w[k * 128 + t];
    ln_stats128(te, red, mean, inv);
    te = lrelu((te - mean) * inv * task_g[t] + task_be[t], 0.01f);
    cf[t] = gf[t]; cf[128 + t] = te;
    __syncthreads();
    float v = v_b1[t];
    for (int k = 0; k < 256; ++k) v += cf[k] * v_w1[k * 128 + t];
    ln_stats128(v, red, mean, inv);
    v = lrelu((v - mean) * inv * v_g[t] + v_be[t], 0.01f);
    float pv = v * v_w2[t];
#pragma unroll
    for (int m = 32; m >= 1; m >>= 1) pv += __shfl_xor(pv, m);
    __syncthreads();
    if ((t & 63) == 0) red[t >> 6] = pv;
    __syncthreads();
    if (t == 0) sc[0] = red[0] + red[1] + v_b2[0];
    float a = a_b1[t];
    for (int k = 0; k < 256; ++k) a += cf[k] * a_w1[k * 128 + t];
    ln_stats128(a, red, mean, inv);
    a = lrelu((a - mean) * inv * a_g[t] + a_be[t], 0.01f);
    hbuf[t] = a;
    __syncthreads();
    if (t < 10) {
        float s = a_b2[t];
        for (int c = 0; c < 128; ++c) s += hbuf[c] * a_w2[c * 10 + t];
        adv[t] = s;
    }
    __syncthreads();
    if (t == 0) {
        float m10 = 0.f;
        for (int o = 0; o < 10; ++o) m10 += adv[o];
        sc[1] = m10 * 0.1f;
    }
    __syncthreads();
    if (t < 10) out[t] = sc[0] + adv[t] - sc[1];
}

extern "C" void kernel_launch(void* const* d_in, const int* in_sizes, int n_in,
                              void* d_out, int out_size, void* d_ws, size_t ws_size,
                              hipStream_t stream)
{
    const float* x        = (const float*)d_in[0];
    const int*   ei       = (const int*)d_in[1];
    const float* ea       = (const float*)d_in[2];
    const float* tf       = (const float*)d_in[3];
    const float* emb_w    = (const float*)d_in[4];
    const float* emb_b    = (const float*)d_in[5];
    const float* emb_g    = (const float*)d_in[6];
    const float* emb_beta = (const float*)d_in[7];
    const float* gat_w    = (const float*)d_in[8];
    const float* gat_as   = (const float*)d_in[9];
    const float* gat_ad   = (const float*)d_in[10];
    const float* gat_bias = (const float*)d_in[11];
    const float* ec_w1    = (const float*)d_in[12];
    const float* ec_b1    = (const float*)d_in[13];
    const float* ec_g1    = (const float*)d_in[14];
    const float* ec_be1   = (const float*)d_in[15];
    const float* ec_w2    = (const float*)d_in[16];
    const float* ec_b2    = (const float*)d_in[17];
    const float* ec_g2    = (const float*)d_in[18];
    const float* ec_be2   = (const float*)d_in[19];
    const float* norm_g   = (const float*)d_in[20];
    const float* norm_b   = (const float*)d_in[21];
    const float* task_w   = (const float*)d_in[22];
    const float* task_b   = (const float*)d_in[23];
    const float* task_g   = (const float*)d_in[24];
    const float* task_be  = (const float*)d_in[25];
    const float* pa_w1    = (const float*)d_in[26];
    const float* pa_b1    = (const float*)d_in[27];
    const float* pa_w2    = (const float*)d_in[28];
    const float* pa_b2    = (const float*)d_in[29];
    const float* v_w1     = (const float*)d_in[30];
    const float* v_b1     = (const float*)d_in[31];
    const float* v_g      = (const float*)d_in[32];
    const float* v_be     = (const float*)d_in[33];
    const float* v_w2     = (const float*)d_in[34];
    const float* v_b2     = (const float*)d_in[35];
    const float* a_w1     = (const float*)d_in[36];
    const float* a_b1     = (const float*)d_in[37];
    const float* a_g      = (const float*)d_in[38];
    const float* a_be     = (const float*)d_in[39];
    const float* a_w2     = (const float*)d_in[40];
    const float* a_b2     = (const float*)d_in[41];

    const int n = in_sizes[0] / 128;   // 25000
    const int e = in_sizes[2];         // 400000
    const int* src = ei;
    const int* dst = ei + e;

    float* ws = (float*)d_ws;
    uint4* wf = (uint4*)ws;                  // 14 * 2048 uint4 = 448KB
    float* base = ws + 14 * 2048 * 4;
    const size_t NR = (size_t)n * 128;
    const size_t NP = (size_t)n * 64;
    float* h    = base;
    float* x0   = base + NR;
    float* xs   = base + 2 * NR;
    unsigned* htp = (unsigned*)(base + 3 * NR);
    unsigned* Apk = htp + NP;
    unsigned* Bpk = Apk + NP;
    float* a_s  = (float*)(Bpk + NP);
    float* a_d  = a_s + (size_t)n * 2;
    float* den  = a_d + (size_t)n * 2;
    float* selfe = den + (size_t)n * 2;
    float* rsA  = selfe + (size_t)n * 2;
    float* rsB  = rsA + n;
    float* score = rsB + n;
    float* stats = score + n;
    float* gf    = stats + 2;
    int*   cnt    = (int*)(gf + 128);
    int*   starts = cnt + n;
    int*   s_src  = starts + (n + 1);
    int*   s_dst  = s_src + e;
    float* s_ea   = (float*)(s_dst + e);
    float* expo   = s_ea + e;            // 2*E

    const int ng64 = (n + 63) / 64;
    const int ng8 = (n + 7) / 8;
    const int ngd = ((e + 7) / 8 + 255) / 256;

    // ---- one-time: counting-sort edges by dst + weight pre-pack ----
    hipMemsetAsync(cnt, 0, (size_t)n * sizeof(int), stream);
    k_hist<<<(e + 255) / 256, 256, 0, stream>>>(dst, cnt, e);
    k_scan<<<1, 1024, 0, stream>>>(cnt, starts, n);
    hipMemcpyAsync(cnt, starts, (size_t)n * sizeof(int), hipMemcpyDeviceToDevice, stream);
    k_scatter<<<(e + 255) / 256, 256, 0, stream>>>(src, dst, ea, cnt, s_src, s_dst, s_ea, e);
    k_prep<<<108, 256, 0, stream>>>(gat_w, ec_w1, ec_w2, emb_w, pa_w1, wf);

    // embedding: h = x0 = lrelu(LN(x @ emb_w + emb_b))
    k_emb<<<ng64, 256, 0, stream>>>(x, wf + (size_t)12 * 2048, emb_b, emb_g, emb_beta, h, x0, n);

    for (int i = 0; i < LL; ++i) {
        if (i == 0) {
            k_gemm3<<<ng64, 256, 0, stream>>>(h, nullptr, nullptr, nullptr,
                                              nullptr, nullptr, nullptr, nullptr,
                                              wf, i, 3 + 2 * i, 4 + 2 * i,
                                              ec_b1 + i * 128, htp, Apk, Bpk, n, 0);
        } else {
            // fused norm of layer i-1: reads xsum + htp(prev) + selfe/denom(prev)
            k_gemm3<<<ng64, 256, 0, stream>>>(xs, htp, selfe, den,
                                              gat_bias + (i - 1) * 128,
                                              norm_g + (i - 1) * 128, norm_b + (i - 1) * 128, x0,
                                              wf, i, 3 + 2 * i, 4 + 2 * i,
                                              ec_b1 + i * 128, htp, Apk, Bpk, n,
                                              (i == 2) ? 2 : 1);
        }
        k_node_scores<<<ng8, 512, 0, stream>>>(htp, Apk, Bpk, gat_as + i * 128, gat_ad + i * 128,
                                               a_s, a_d, den, selfe, rsA, rsB, n);
        k_edge_denom2<<<ngd, 256, 0, stream>>>(s_src, s_dst, a_s, a_d, den, expo,
                                               (float4*)xs, n * 32, e);
        k_edge_main<<<(e + EB - 1) / EB, 512, 0, stream>>>(Apk, Bpk, htp, s_src, s_dst, s_ea,
                                                           expo, den,
                                                           wf + (size_t)(9 + i) * 2048,
                                                           rsA, rsB,
                                                           ec_g1 + i * 128, ec_be1 + i * 128,
                                                           ec_b2 + i * 128, ec_g2 + i * 128, ec_be2 + i * 128,
                                                           xs, e);
    }
    // final norm (layer 2, residual) -> h for pooling
    k_norm8<<<ng8, 512, 0, stream>>>(xs, htp, selfe, den, gat_bias + 2 * 128,
                                     norm_g + 2 * 128, norm_b + 2 * 128, x0, h, n, 2);

    k_pool<<<ng64, 256, 0, stream>>>(h, wf + (size_t)13 * 2048, pa_b1, pa_w2, pa_b2, score, n);
    k_softmax_reduce<<<1, 256, 0, stream>>>(score, stats, gf, n);
    k_gf<<<200, 128, 0, stream>>>(h, score, stats, gf, n);
    k_head<<<1, 128, 0, stream>>>(gf, tf, task_w, task_b, task_g, task_be,
                                  v_w1, v_b1, v_g, v_be, v_w2, v_b2,
                                  a_w1, a_b1, a_g, a_be, a_w2, a_b2,
                                  (float*)d_out);
}